// Round 7
// baseline (193.685 us; speedup 1.0000x reference)
//
#include <hip/hip_runtime.h>

// GateLoopOperator, MI355X. Round 7:
//  - k_S3: fused S-GEMM restructured for 2-blocks/CU co-residency (grid 512 = ck2 x 8 xt),
//    M=256 per block, bf16-packed v in LDS, dbuf B panel, conflict-aware XOR swizzles.
//  - k_h: cooperative coalesced float4 staging of the Aon slice into LDS.
//
// Pipeline:
//  k_prep : A2[m][1536] bf16 = [hi(xp) | hi(xp) | lo(xp)]
//  k_cvtW : Bw[j][1536] bf16 = [hi(W) | lo | hi] (pre-permuted rows)
//  k_kqv3 : k/q/v f32 = A2 @ Bw^T (split-bf16 MFMA => f32 quality)
//  k_S3   : Spart[(ck2,xt)][m][n] = sum_{x in slab, y} bf16(k[m,x]v[m,y]) * bf16(Ano[...,n])
//  k_Sred : S[m][n] = sum over 512 slabs
//  k_scan : u[bp,n] = S[bp,30] + sum_i Ann^(2^i) @ S[bp,29-i] (early-exit)
//  k_h    : h = Aoo*k_last*v_last + Aon . u   (LDS-staged Aon)
//  k_y    : y = q . h

#define ANO_C_STR 3276800
#define ANO_K_STR 409600
#define ANO_X_STR 6400

typedef __attribute__((ext_vector_type(8))) short bf16x8;
typedef __attribute__((ext_vector_type(4))) float f32x4;
typedef __attribute__((ext_vector_type(4))) unsigned short u16x4;

__device__ __forceinline__ float4 ld4(const float* p) { return *(const float4*)p; }

__device__ __forceinline__ unsigned short f2bf(float f) {  // RNE
  unsigned u = __float_as_uint(f);
  unsigned r = (u + 0x7fffu + ((u >> 16) & 1u)) >> 16;
  return (unsigned short)r;
}
__device__ __forceinline__ float bf2f(unsigned short b) {
  return __uint_as_float(((unsigned)b) << 16);
}
// 2 f32 -> u32 of 2 bf16 (lo -> low half). Used identically on A and B.
__device__ __forceinline__ unsigned cvtpk(float lo, float hi) {
  unsigned r;
  asm("v_cvt_pk_bf16_f32 %0, %1, %2" : "=v"(r) : "v"(lo), "v"(hi));
  return r;
}
__device__ __forceinline__ float bflo(unsigned u) { return __uint_as_float(u << 16); }
__device__ __forceinline__ float bfhi(unsigned u) { return __uint_as_float(u & 0xffff0000u); }

// ---------------------------------------------------------------- k_prep
__global__ __launch_bounds__(256) void k_prep(const float* __restrict__ X,
                                              unsigned short* __restrict__ A2) {
  __shared__ float xs[512];
  const int m = blockIdx.x;
  const int tid = threadIdx.x;
  for (int f = tid; f < 512; f += 256) xs[f] = X[m * 512 + f];
  __syncthreads();
  for (int f = tid; f < 512; f += 256) {
    float v = xs[((f & 7) << 6) | (f >> 3)];
    unsigned short hi = f2bf(v);
    unsigned short lo = f2bf(v - bf2f(hi));
    A2[(size_t)m * 1536 + f] = hi;
    A2[(size_t)m * 1536 + 512 + f] = hi;
    A2[(size_t)m * 1536 + 1024 + f] = lo;
  }
}

// ---------------------------------------------------------------- k_cvtW
__global__ __launch_bounds__(128) void k_cvtW(const float* __restrict__ Km,
                                              const float* __restrict__ Qm,
                                              const float* __restrict__ Vm,
                                              unsigned short* __restrict__ Bw) {
  const int j = blockIdx.x;  // mat*512 + o
  const int mat = j >> 9, o = j & 511;
  const int r = ((o & 63) << 3) | (o >> 6);
  const float* W = ((mat == 0) ? Km : ((mat == 1) ? Qm : Vm)) + (size_t)r * 512;
  const int tid = threadIdx.x;
  float4 v = ld4(W + tid * 4);
  u16x4 hi, lo;
  float vv[4] = {v.x, v.y, v.z, v.w};
#pragma unroll
  for (int e = 0; e < 4; ++e) {
    hi[e] = f2bf(vv[e]);
    lo[e] = f2bf(vv[e] - bf2f(hi[e]));
  }
  *(u16x4*)&Bw[(size_t)j * 1536 + tid * 4] = hi;
  *(u16x4*)&Bw[(size_t)j * 1536 + 512 + tid * 4] = lo;
  *(u16x4*)&Bw[(size_t)j * 1536 + 1024 + tid * 4] = hi;
}

// ---------------------------------------------------------------- k_kqv3
__global__ __launch_bounds__(256) void k_kqv3(const unsigned short* __restrict__ A2,
                                              const unsigned short* __restrict__ Bw,
                                              float* __restrict__ kqvF) {
  __shared__ __align__(16) unsigned short Asm[128 * 64];
  __shared__ __align__(16) unsigned short Bsm[128 * 64];
  const int bid = blockIdx.x;  // 24
  const int mt = bid & 1, jt = bid >> 1;
  const int m0 = mt * 128, j0 = jt * 128;
  const int tid = threadIdx.x;
  const int lane = tid & 63;
  const int w = tid >> 6;
  const int wm = w >> 1, wn = w & 1;

  f32x4 acc[4][4];
#pragma unroll
  for (int a = 0; a < 4; ++a)
#pragma unroll
    for (int b = 0; b < 4; ++b) acc[a][b] = (f32x4)(0.f);

  for (int kc = 0; kc < 1536; kc += 64) {
#pragma unroll
    for (int cch = 0; cch < 4; ++cch) {
      int sid = cch * 256 + tid;
      int r = sid >> 3, c8 = sid & 7;
      int srcc = c8 ^ (r & 7);
      const unsigned short* ga = A2 + (size_t)(m0 + r) * 1536 + kc + srcc * 8;
      __builtin_amdgcn_global_load_lds((const __attribute__((address_space(1))) unsigned int*)ga,
                                       (__attribute__((address_space(3))) unsigned int*)(&Asm[sid * 8]),
                                       16, 0, 0);
      const unsigned short* gb = Bw + (size_t)(j0 + r) * 1536 + kc + srcc * 8;
      __builtin_amdgcn_global_load_lds((const __attribute__((address_space(1))) unsigned int*)gb,
                                       (__attribute__((address_space(3))) unsigned int*)(&Bsm[sid * 8]),
                                       16, 0, 0);
    }
    __syncthreads();
#pragma unroll
    for (int ks = 0; ks < 2; ++ks) {
      bf16x8 af[4], bfr[4];
#pragma unroll
      for (int mf = 0; mf < 4; ++mf) {
        int r = wm * 64 + mf * 16 + (lane & 15);
        int slot = (ks * 4 + (lane >> 4)) ^ (r & 7);
        af[mf] = *(const bf16x8*)&Asm[r * 64 + slot * 8];
      }
#pragma unroll
      for (int nf = 0; nf < 4; ++nf) {
        int r = wn * 64 + nf * 16 + (lane & 15);
        int slot = (ks * 4 + (lane >> 4)) ^ (r & 7);
        bfr[nf] = *(const bf16x8*)&Bsm[r * 64 + slot * 8];
      }
#pragma unroll
      for (int mf = 0; mf < 4; ++mf)
#pragma unroll
        for (int nf = 0; nf < 4; ++nf)
          acc[mf][nf] = __builtin_amdgcn_mfma_f32_16x16x32_bf16(af[mf], bfr[nf], acc[mf][nf], 0, 0, 0);
    }
    __syncthreads();
  }
#pragma unroll
  for (int mf = 0; mf < 4; ++mf)
#pragma unroll
    for (int nf = 0; nf < 4; ++nf) {
      int col = j0 + wn * 64 + nf * 16 + (lane & 15);
      int mat = col >> 9, o = col & 511;
      float* Outp = kqvF + (size_t)mat * 131072;
#pragma unroll
      for (int r = 0; r < 4; ++r) {
        int row = m0 + wm * 64 + mf * 16 + (lane >> 4) * 4 + r;
        Outp[(size_t)row * 512 + o] = acc[mf][nf][r];
      }
    }
}

// ---------------------------------------------------------------- k_S3
// Spart[bid][m][n] = sum_{x in [xt*8, xt*8+8), y} bf16(k[m,cx]*v[m,k2y]) * bf16(Ano[c,k2,x,y,n])
// grid 512 = ck2(64) x xt(8). 256 thr / 4 waves; wave w owns m-rows w*64..+64.
// LDS 68KB -> 2 blocks/CU co-resident (latency hiding across blocks).
// vslw: word (m, yw) at m*32 + (yw ^ ((m&7)<<2))        [read: slot = chunk ^ (m&7)]
// Bp  : word (n, w)  at n*32 + (w ^ (s2(n)<<2)), s2(n)=(n^(n>>3))&7  [read: slot = chunk ^ s2(r)]
__global__ __launch_bounds__(256, 2) void k_S3(const float* __restrict__ kw,
                                               const float* __restrict__ vw,
                                               const float* __restrict__ Ano,
                                               float* __restrict__ Spart) {
  __shared__ float ksl[8 * 256];                      // 8 KB   [xi][m]
  __shared__ unsigned vslw[256 * 32];                 // 32 KB
  __shared__ __align__(16) unsigned Bp[2][112 * 32];  // 28 KB dbuf
  const int bid = blockIdx.x;  // 512
  const int ck2 = bid & 63, xt = bid >> 6;
  const int c = ck2 >> 3, k2 = ck2 & 7;
  const int x0 = xt * 8;
  const int tid = threadIdx.x;
  const int lane = tid & 63;
  const int w = tid >> 6;
  const int l15 = lane & 15, hig = lane >> 4;

  const float* slab = Ano + (size_t)c * ANO_C_STR + (size_t)k2 * ANO_K_STR + (size_t)x0 * ANO_X_STR;

  // ---- stage k slice [8x][256m]
  {
    const float* kp = kw + (size_t)tid * 512 + c * 64 + x0;
    float4 ka = ld4(kp), kb = ld4(kp + 4);
    ksl[0 * 256 + tid] = ka.x; ksl[1 * 256 + tid] = ka.y;
    ksl[2 * 256 + tid] = ka.z; ksl[3 * 256 + tid] = ka.w;
    ksl[4 * 256 + tid] = kb.x; ksl[5 * 256 + tid] = kb.y;
    ksl[6 * 256 + tid] = kb.z; ksl[7 * 256 + tid] = kb.w;
  }
  // ---- stage v slice as packed bf16 pairs (coalesced f4 loads)
#pragma unroll
  for (int p = 0; p < 16; ++p) {
    int id = p * 256 + tid;
    int m = id >> 4, yq = id & 15;
    float4 v4 = ld4(vw + (size_t)m * 512 + k2 * 64 + yq * 4);
    unsigned sw = ((unsigned)m & 7u) << 2;
    int base = m * 32 + ((yq * 2) ^ (int)sw);  // sw bits>=2 -> +1 stays adjacent
    vslw[base] = cvtpk(v4.x, v4.y);
    vslw[base + 1] = cvtpk(v4.z, v4.w);
  }

  // ---- per-thread B staging units: u=(w=u/25 ypair, nq=u%25 n-quad); 800 units
  int goff[4];
  int iw[4][4];
#pragma unroll
  for (int j = 0; j < 4; ++j) {
    int u = (j < 3) ? (tid + j * 256) : (768 + (tid & 31));
    int wp = u / 25, nq = u - wp * 25;
    goff[j] = wp * 200 + nq * 4;
#pragma unroll
    for (int e = 0; e < 4; ++e) {
      int n = nq * 4 + e;
      int s2 = (n ^ (n >> 3)) & 7;
      iw[j][e] = n * 32 + (wp ^ (s2 << 2));
    }
  }
  const bool has4 = (tid >= 224);

  // ---- prefetch x = 0
  float4 r0[4], r1[4];
#pragma unroll
  for (int j = 0; j < 4; ++j)
    if (j < 3 || has4) {
      r0[j] = ld4(slab + goff[j]);
      r1[j] = ld4(slab + goff[j] + 100);
    }

  f32x4 acc[4][7];
#pragma unroll
  for (int mf = 0; mf < 4; ++mf)
#pragma unroll
    for (int nf = 0; nf < 7; ++nf) acc[mf][nf] = (f32x4)(0.f);

  for (int x = 0; x < 8; ++x) {
    unsigned* bp = &Bp[x & 1][0];
    // write panel x (from regs)
#pragma unroll
    for (int j = 0; j < 4; ++j)
      if (j < 3 || has4) {
        bp[iw[j][0]] = cvtpk(r0[j].x, r1[j].x);
        bp[iw[j][1]] = cvtpk(r0[j].y, r1[j].y);
        bp[iw[j][2]] = cvtpk(r0[j].z, r1[j].z);
        bp[iw[j][3]] = cvtpk(r0[j].w, r1[j].w);
      }
    // issue loads for x+1 (land during this step's MFMA)
    if (x < 7) {
      const float* px = slab + (size_t)(x + 1) * ANO_X_STR;
#pragma unroll
      for (int j = 0; j < 4; ++j)
        if (j < 3 || has4) {
          r0[j] = ld4(px + goff[j]);
          r1[j] = ld4(px + goff[j] + 100);
        }
    }
    __syncthreads();

    const unsigned short* bp16 = (const unsigned short*)bp;
#pragma unroll
    for (int ks = 0; ks < 2; ++ks) {
      int chunk = ks * 4 + hig;
      // B-frags (shared across mf)
      bf16x8 bfr[7];
#pragma unroll
      for (int nf = 0; nf < 7; ++nf) {
        int r = nf * 16 + l15;
        int slot = chunk ^ ((r ^ (r >> 3)) & 7);
        bfr[nf] = *(const bf16x8*)&bp16[r * 64 + slot * 8];
      }
#pragma unroll
      for (int mf = 0; mf < 4; ++mf) {
        int m = w * 64 + mf * 16 + l15;
        float kx = ksl[x * 256 + m];
        int slot = chunk ^ (m & 7);
        const unsigned* vp = &vslw[m * 32 + slot * 4];
        unsigned v0 = vp[0], v1 = vp[1], v2 = vp[2], v3 = vp[3];
        union { unsigned u[4]; bf16x8 v; } fu;
        fu.u[0] = cvtpk(kx * bflo(v0), kx * bfhi(v0));
        fu.u[1] = cvtpk(kx * bflo(v1), kx * bfhi(v1));
        fu.u[2] = cvtpk(kx * bflo(v2), kx * bfhi(v2));
        fu.u[3] = cvtpk(kx * bflo(v3), kx * bfhi(v3));
#pragma unroll
        for (int nf = 0; nf < 7; ++nf)
          acc[mf][nf] = __builtin_amdgcn_mfma_f32_16x16x32_bf16(fu.v, bfr[nf], acc[mf][nf], 0, 0, 0);
      }
    }
    __syncthreads();
  }

  float* sp = Spart + (size_t)bid * 25600;
#pragma unroll
  for (int mf = 0; mf < 4; ++mf)
#pragma unroll
    for (int nf = 0; nf < 7; ++nf) {
      int n = nf * 16 + l15;
      if (n < 100) {
#pragma unroll
        for (int rr = 0; rr < 4; ++rr) {
          int m = w * 64 + mf * 16 + hig * 4 + rr;
          sp[(size_t)m * 100 + n] = acc[mf][nf][rr];
        }
      }
    }
}

// ---------------------------------------------------------------- k_Sred
__global__ __launch_bounds__(512) void k_Sred(const float* __restrict__ Spart,
                                              float* __restrict__ S) {
  __shared__ float red[512];
  const int m = blockIdx.x;
  const int tid = threadIdx.x;
  const int q = tid >> 7, n = tid & 127;
  float acc = 0.f;
  if (n < 100) {
    const float* p = Spart + (size_t)q * 128 * 25600 + (size_t)m * 100 + n;
#pragma unroll 8
    for (int s = 0; s < 128; ++s) acc += p[(size_t)s * 25600];
  }
  red[tid] = acc;
  __syncthreads();
  if (tid < 100)
    S[m * 100 + tid] = red[tid] + red[128 + tid] + red[256 + tid] + red[384 + tid];
}

// ---------------------------------------------------------------- k_scan
__global__ __launch_bounds__(1024) void k_scan(const float* __restrict__ Ann,
                                               const float* __restrict__ Sg,
                                               float* __restrict__ ug) {
  __shared__ float Abuf[10000];
  __shared__ float s_s[800];
  __shared__ float u_s[800];
  __shared__ float red[16];
  __shared__ float gmax_s;
  const int tid = threadIdx.x;

  float lmax0 = 0.f;
  for (int f = tid; f < 10000; f += 1024) {
    float a = Ann[f];
    Abuf[f] = a;
    lmax0 = fmaxf(lmax0, fabsf(a));
  }
  for (int f = tid; f < 800; f += 1024) {
    int bp = f / 100, n = f - bp * 100;
    u_s[f] = Sg[(bp * 32 + 30) * 100 + n];
  }
#pragma unroll
  for (int off = 32; off > 0; off >>= 1) lmax0 = fmaxf(lmax0, __shfl_down(lmax0, off, 64));
  if ((tid & 63) == 0) red[tid >> 6] = lmax0;
  __syncthreads();
  if (tid == 0) {
    float mx = 0.f;
    for (int wv = 0; wv < 16; ++wv) mx = fmaxf(mx, red[wv]);
    gmax_s = mx;
  }
  const int ri = tid / 25;
  const int cj = tid - ri * 25;
  const bool sqact = (tid < 625);
  __syncthreads();

  for (int i = 0; i < 30; ++i) {
    const int t = 29 - i;
    for (int f = tid; f < 800; f += 1024) {
      int bp = f / 100, n = f - bp * 100;
      s_s[f] = Sg[(bp * 32 + t) * 100 + n];
    }
    __syncthreads();
    if (tid < 800) {
      int bp = tid / 100, n = tid - bp * 100;
      const float* Ar = &Abuf[n * 100];
      const float* sr = &s_s[bp * 100];
      float a0 = 0.f;
#pragma unroll
      for (int mm = 0; mm < 100; mm += 4) {
        float4 a4 = ld4(Ar + mm);
        float4 s4 = ld4(sr + mm);
        a0 += a4.x * s4.x + a4.y * s4.y + a4.z * s4.z + a4.w * s4.w;
      }
      u_s[tid] += a0;
    }
    if (i == 29) break;
    if (gmax_s < 1e-6f) break;

    float acc2[4][4];
    float lmax = 0.f;
    if (sqact) {
#pragma unroll
      for (int a = 0; a < 4; ++a)
#pragma unroll
        for (int b = 0; b < 4; ++b) acc2[a][b] = 0.f;
      for (int mm = 0; mm < 100; mm += 4) {
        float av[4][4], bv[4][4];
#pragma unroll
        for (int ii = 0; ii < 4; ++ii)
          *(float4*)&av[ii][0] = ld4(&Abuf[(ri * 4 + ii) * 100 + mm]);
#pragma unroll
        for (int mi = 0; mi < 4; ++mi)
          *(float4*)&bv[mi][0] = ld4(&Abuf[(mm + mi) * 100 + cj * 4]);
#pragma unroll
        for (int ii = 0; ii < 4; ++ii)
#pragma unroll
          for (int mi = 0; mi < 4; ++mi)
#pragma unroll
            for (int qq = 0; qq < 4; ++qq) acc2[ii][qq] += av[ii][mi] * bv[mi][qq];
      }
    }
    __syncthreads();
    if (sqact) {
#pragma unroll
      for (int ii = 0; ii < 4; ++ii) {
        float4 wv = make_float4(acc2[ii][0], acc2[ii][1], acc2[ii][2], acc2[ii][3]);
        *(float4*)&Abuf[(ri * 4 + ii) * 100 + cj * 4] = wv;
        lmax = fmaxf(lmax, fmaxf(fmaxf(fabsf(wv.x), fabsf(wv.y)), fmaxf(fabsf(wv.z), fabsf(wv.w))));
      }
    }
#pragma unroll
    for (int off = 32; off > 0; off >>= 1) lmax = fmaxf(lmax, __shfl_down(lmax, off, 64));
    if ((tid & 63) == 0) red[tid >> 6] = lmax;
    __syncthreads();
    if (tid == 0) {
      float mx = 0.f;
      for (int wv = 0; wv < 16; ++wv) mx = fmaxf(mx, red[wv]);
      gmax_s = mx;
    }
    __syncthreads();
  }
  __syncthreads();
  for (int f = tid; f < 800; f += 1024) ug[f] = u_s[f];
}

// ---------------------------------------------------------------- k_h
// h[bp,a,b,g,d] = Aoo*k_last*v_last + sum_n Aon[(a,b,g,d)][n]*u[bp][n]
// Aon slice (6400 f32) staged coalesced into LDS, then 2-way-free LDS reads.
__global__ __launch_bounds__(256) void k_h(const float* __restrict__ Aon,
                                           const float* __restrict__ Aoo,
                                           const float* __restrict__ kw,
                                           const float* __restrict__ vw,
                                           const float* __restrict__ ug,
                                           float* __restrict__ h) {
  __shared__ float aon_s[6400];
  __shared__ float uT[100 * 8];
  __shared__ float aoo_s[64];
  __shared__ float kl_s[8];
  __shared__ float vl_s[8 * 64];
  __shared__ float part[4 * 64 * 8];
  const int bid = blockIdx.x;  // (a*8+b)*64+g
  const int g = bid & 63, b = (bid >> 6) & 7, a = bid >> 9;
  const int tid = threadIdx.x;

  {
    const float* ab = Aon + (size_t)bid * 6400;
#pragma unroll
    for (int p = 0; p < 7; ++p) {
      int id = p * 256 + tid;
      if (id < 1600) *(float4*)&aon_s[id * 4] = ld4(ab + (size_t)id * 4);
    }
  }
  for (int f = tid; f < 800; f += 256) {
    int n = f >> 3, bp = f & 7;
    uT[f] = ug[bp * 100 + n];
  }
  if (tid < 64) aoo_s[tid] = Aoo[(size_t)bid * 64 + tid];
  if (tid < 8) kl_s[tid] = kw[(size_t)(tid * 32 + 31) * 512 + a * 64 + g];
  for (int f = tid; f < 512; f += 256) {
    int bp = f >> 6, d = f & 63;
    vl_s[f] = vw[(size_t)(bp * 32 + 31) * 512 + b * 64 + d];
  }
  __syncthreads();

  const int ng = tid & 3, d = tid >> 2;
  const float* basep = &aon_s[d * 100 + ng * 25];
  float acc8[8];
#pragma unroll
  for (int bb = 0; bb < 8; ++bb) acc8[bb] = 0.f;
#pragma unroll
  for (int q = 0; q < 25; ++q) {
    int n = ng * 25 + q;
    float av = basep[q];
    float4 u0 = ld4(&uT[n * 8]);
    float4 u1 = ld4(&uT[n * 8 + 4]);
    acc8[0] += av * u0.x; acc8[1] += av * u0.y; acc8[2] += av * u0.z; acc8[3] += av * u0.w;
    acc8[4] += av * u1.x; acc8[5] += av * u1.y; acc8[6] += av * u1.z; acc8[7] += av * u1.w;
  }
  {
    float* pp = &part[(ng * 64 + d) * 8];
    *(float4*)pp = make_float4(acc8[0], acc8[1], acc8[2], acc8[3]);
    *(float4*)(pp + 4) = make_float4(acc8[4], acc8[5], acc8[6], acc8[7]);
  }
  __syncthreads();
  for (int o = tid; o < 512; o += 256) {
    int bp = o >> 6, d2 = o & 63;
    float s = aoo_s[d2] * kl_s[bp] * vl_s[bp * 64 + d2];
#pragma unroll
    for (int n2 = 0; n2 < 4; ++n2) s += part[(n2 * 64 + d2) * 8 + bp];
    h[(size_t)bp * 262144 + (size_t)bid * 64 + d2] = s;
  }
}

// ---------------------------------------------------------------- k_y
__global__ __launch_bounds__(256) void k_y(const float* __restrict__ qw,
                                           const float* __restrict__ h,
                                           float* __restrict__ out) {
  __shared__ float qT[32 * 32];
  __shared__ float Hs[32 * 64];
  const int bid = blockIdx.x;  // bp*8 + b
  const int bp = bid >> 3, b = bid & 7;
  const int tid = threadIdx.x;
  const int r2 = tid >> 4, c2 = tid & 15;
  const size_t hbase = (size_t)bp * 262144 + (size_t)b * 4096;
  float acc[2][4];
#pragma unroll
  for (int i = 0; i < 2; ++i)
#pragma unroll
    for (int q = 0; q < 4; ++q) acc[i][q] = 0.f;

  for (int kc = 0; kc < 512; kc += 32) {
    {
      int t = tid & 31, kq = tid >> 5;
      float4 qv = ld4(qw + (size_t)(bp * 32 + t) * 512 + kc + kq * 4);
      qT[(kq * 4 + 0) * 32 + t] = qv.x;
      qT[(kq * 4 + 1) * 32 + t] = qv.y;
      qT[(kq * 4 + 2) * 32 + t] = qv.z;
      qT[(kq * 4 + 3) * 32 + t] = qv.w;
    }
#pragma unroll
    for (int i2 = 0; i2 < 2; ++i2) {
      int fid = i2 * 256 + tid;
      int kk = fid >> 4, xq = (fid & 15) * 4;
      int row = kc + kk;
      int A = row >> 6, G = row & 63;
      float4 hv = ld4(h + hbase + (size_t)A * 32768 + (size_t)G * 64 + xq);
      *(float4*)&Hs[kk * 64 + xq] = hv;
    }
    __syncthreads();
#pragma unroll
    for (int kk = 0; kk < 32; ++kk) {
      float2 q2 = *(const float2*)&qT[kk * 32 + r2 * 2];
      float4 h4 = ld4(&Hs[kk * 64 + c2 * 4]);
      acc[0][0] += q2.x * h4.x; acc[0][1] += q2.x * h4.y; acc[0][2] += q2.x * h4.z; acc[0][3] += q2.x * h4.w;
      acc[1][0] += q2.y * h4.x; acc[1][1] += q2.y * h4.y; acc[1][2] += q2.y * h4.z; acc[1][3] += q2.y * h4.w;
    }
    __syncthreads();
  }
#pragma unroll
  for (int i = 0; i < 2; ++i) {
    float4 v = make_float4(acc[i][0], acc[i][1], acc[i][2], acc[i][3]);
    *(float4*)&out[(size_t)(bp * 32 + r2 * 2 + i) * 512 + b * 64 + c2 * 4] = v;
  }
}

// ---------------------------------------------------------------- launch
extern "C" void kernel_launch(void* const* d_in, const int* in_sizes, int n_in,
                              void* d_out, int out_size, void* d_ws, size_t ws_size,
                              hipStream_t stream) {
  const float* x   = (const float*)d_in[0];
  const float* K   = (const float*)d_in[1];
  const float* Q   = (const float*)d_in[2];
  const float* V   = (const float*)d_in[3];
  const float* Aoo = (const float*)d_in[4];
  const float* Ann = (const float*)d_in[5];
  const float* Aon = (const float*)d_in[6];
  const float* Ano = (const float*)d_in[7];
  float* out = (float*)d_out;

  float* ws = (float*)d_ws;
  float* kw  = ws;                                          // 131072
  float* qw  = kw + 131072;                                 // 131072
  float* vw  = qw + 131072;                                 // 131072
  float* S   = ws + 458752;                                 // 25600
  float* u   = S + 25600;                                   // 800
  unsigned short* A2  = (unsigned short*)(ws + 485152);     // 393216 u16
  unsigned short* Bw  = (unsigned short*)(ws + 681760);     // 2359296 u16
  float* h     = ws + 1861408;                              // 2097152
  float* Spart = ws + 3958560;                              // 13107200 (52.4 MB)

  k_prep<<<dim3(256), dim3(256), 0, stream>>>(x, A2);
  k_cvtW<<<dim3(1536), dim3(128), 0, stream>>>(K, Q, V, Bw);
  k_kqv3<<<dim3(24), dim3(256), 0, stream>>>(A2, Bw, kw);
  k_S3<<<dim3(512), dim3(256), 0, stream>>>(kw, vw, Ano, Spart);
  k_Sred<<<dim3(256), dim3(512), 0, stream>>>(Spart, S);
  k_scan<<<dim3(1), dim3(1024), 0, stream>>>(Ann, S, u);
  k_h<<<dim3(4096), dim3(256), 0, stream>>>(Aon, Aoo, kw, vw, u, h);
  k_y<<<dim3(64), dim3(256), 0, stream>>>(qw, h, out);
}

// Round 8
// 185.169 us; speedup vs baseline: 1.0460x; 1.0460x over previous
//
#include <hip/hip_runtime.h>

// GateLoopOperator, MI355X. Round 8:
//  - k_S4: fused S-GEMM with 2-deep register pipeline (named rA/rB batches, uniform
//    8xfloat4 loads/thread -> compiler emits counted vmcnt), ONE barrier per x-step,
//    grid 256 = 64 ck2 x 4 xt (disjoint Ano slabs, read exactly once), 16 x-steps.
//  - Spart: 256 slabs (26 MB) -> k_Sred ~6 us.
//
// Pipeline:
//  k_prep : A2[m][1536] bf16 = [hi(xp) | hi(xp) | lo(xp)]
//  k_cvtW : Bw[j][1536] bf16 = [hi(W) | lo | hi] (pre-permuted rows)
//  k_kqv3 : k/q/v f32 = A2 @ Bw^T (split-bf16 MFMA => f32 quality)
//  k_S4   : Spart[(xt,ck2)][m][n] = sum_{x in slab, y} bf16(k[m,x]v[m,y]) * bf16(Ano[...,n])
//  k_Sred : S[m][n] = sum over 256 slabs
//  k_scan : u[bp,n] = S[bp,30] + sum_i Ann^(2^i) @ S[bp,29-i] (early-exit)
//  k_h    : h = Aoo*k_last*v_last + Aon . u   (LDS-staged Aon)
//  k_y    : y = q . h

#define ANO_C_STR 3276800
#define ANO_K_STR 409600
#define ANO_X_STR 6400

typedef __attribute__((ext_vector_type(8))) short bf16x8;
typedef __attribute__((ext_vector_type(4))) float f32x4;
typedef __attribute__((ext_vector_type(4))) unsigned short u16x4;

__device__ __forceinline__ float4 ld4(const float* p) { return *(const float4*)p; }

__device__ __forceinline__ unsigned short f2bf(float f) {  // RNE
  unsigned u = __float_as_uint(f);
  unsigned r = (u + 0x7fffu + ((u >> 16) & 1u)) >> 16;
  return (unsigned short)r;
}
__device__ __forceinline__ float bf2f(unsigned short b) {
  return __uint_as_float(((unsigned)b) << 16);
}
// 2 f32 -> u32 of 2 bf16 (lo -> low half). Used identically on A and B.
__device__ __forceinline__ unsigned cvtpk(float lo, float hi) {
  unsigned r;
  asm("v_cvt_pk_bf16_f32 %0, %1, %2" : "=v"(r) : "v"(lo), "v"(hi));
  return r;
}
__device__ __forceinline__ float bflo(unsigned u) { return __uint_as_float(u << 16); }
__device__ __forceinline__ float bfhi(unsigned u) { return __uint_as_float(u & 0xffff0000u); }

// ---------------------------------------------------------------- k_prep
__global__ __launch_bounds__(256) void k_prep(const float* __restrict__ X,
                                              unsigned short* __restrict__ A2) {
  __shared__ float xs[512];
  const int m = blockIdx.x;
  const int tid = threadIdx.x;
  for (int f = tid; f < 512; f += 256) xs[f] = X[m * 512 + f];
  __syncthreads();
  for (int f = tid; f < 512; f += 256) {
    float v = xs[((f & 7) << 6) | (f >> 3)];
    unsigned short hi = f2bf(v);
    unsigned short lo = f2bf(v - bf2f(hi));
    A2[(size_t)m * 1536 + f] = hi;
    A2[(size_t)m * 1536 + 512 + f] = hi;
    A2[(size_t)m * 1536 + 1024 + f] = lo;
  }
}

// ---------------------------------------------------------------- k_cvtW
__global__ __launch_bounds__(128) void k_cvtW(const float* __restrict__ Km,
                                              const float* __restrict__ Qm,
                                              const float* __restrict__ Vm,
                                              unsigned short* __restrict__ Bw) {
  const int j = blockIdx.x;  // mat*512 + o
  const int mat = j >> 9, o = j & 511;
  const int r = ((o & 63) << 3) | (o >> 6);
  const float* W = ((mat == 0) ? Km : ((mat == 1) ? Qm : Vm)) + (size_t)r * 512;
  const int tid = threadIdx.x;
  float4 v = ld4(W + tid * 4);
  u16x4 hi, lo;
  float vv[4] = {v.x, v.y, v.z, v.w};
#pragma unroll
  for (int e = 0; e < 4; ++e) {
    hi[e] = f2bf(vv[e]);
    lo[e] = f2bf(vv[e] - bf2f(hi[e]));
  }
  *(u16x4*)&Bw[(size_t)j * 1536 + tid * 4] = hi;
  *(u16x4*)&Bw[(size_t)j * 1536 + 512 + tid * 4] = lo;
  *(u16x4*)&Bw[(size_t)j * 1536 + 1024 + tid * 4] = hi;
}

// ---------------------------------------------------------------- k_kqv3
__global__ __launch_bounds__(256) void k_kqv3(const unsigned short* __restrict__ A2,
                                              const unsigned short* __restrict__ Bw,
                                              float* __restrict__ kqvF) {
  __shared__ __align__(16) unsigned short Asm[128 * 64];
  __shared__ __align__(16) unsigned short Bsm[128 * 64];
  const int bid = blockIdx.x;  // 24
  const int mt = bid & 1, jt = bid >> 1;
  const int m0 = mt * 128, j0 = jt * 128;
  const int tid = threadIdx.x;
  const int lane = tid & 63;
  const int w = tid >> 6;
  const int wm = w >> 1, wn = w & 1;

  f32x4 acc[4][4];
#pragma unroll
  for (int a = 0; a < 4; ++a)
#pragma unroll
    for (int b = 0; b < 4; ++b) acc[a][b] = (f32x4)(0.f);

  for (int kc = 0; kc < 1536; kc += 64) {
#pragma unroll
    for (int cch = 0; cch < 4; ++cch) {
      int sid = cch * 256 + tid;
      int r = sid >> 3, c8 = sid & 7;
      int srcc = c8 ^ (r & 7);
      const unsigned short* ga = A2 + (size_t)(m0 + r) * 1536 + kc + srcc * 8;
      __builtin_amdgcn_global_load_lds((const __attribute__((address_space(1))) unsigned int*)ga,
                                       (__attribute__((address_space(3))) unsigned int*)(&Asm[sid * 8]),
                                       16, 0, 0);
      const unsigned short* gb = Bw + (size_t)(j0 + r) * 1536 + kc + srcc * 8;
      __builtin_amdgcn_global_load_lds((const __attribute__((address_space(1))) unsigned int*)gb,
                                       (__attribute__((address_space(3))) unsigned int*)(&Bsm[sid * 8]),
                                       16, 0, 0);
    }
    __syncthreads();
#pragma unroll
    for (int ks = 0; ks < 2; ++ks) {
      bf16x8 af[4], bfr[4];
#pragma unroll
      for (int mf = 0; mf < 4; ++mf) {
        int r = wm * 64 + mf * 16 + (lane & 15);
        int slot = (ks * 4 + (lane >> 4)) ^ (r & 7);
        af[mf] = *(const bf16x8*)&Asm[r * 64 + slot * 8];
      }
#pragma unroll
      for (int nf = 0; nf < 4; ++nf) {
        int r = wn * 64 + nf * 16 + (lane & 15);
        int slot = (ks * 4 + (lane >> 4)) ^ (r & 7);
        bfr[nf] = *(const bf16x8*)&Bsm[r * 64 + slot * 8];
      }
#pragma unroll
      for (int mf = 0; mf < 4; ++mf)
#pragma unroll
        for (int nf = 0; nf < 4; ++nf)
          acc[mf][nf] = __builtin_amdgcn_mfma_f32_16x16x32_bf16(af[mf], bfr[nf], acc[mf][nf], 0, 0, 0);
    }
    __syncthreads();
  }
#pragma unroll
  for (int mf = 0; mf < 4; ++mf)
#pragma unroll
    for (int nf = 0; nf < 4; ++nf) {
      int col = j0 + wn * 64 + nf * 16 + (lane & 15);
      int mat = col >> 9, o = col & 511;
      float* Outp = kqvF + (size_t)mat * 131072;
#pragma unroll
      for (int r = 0; r < 4; ++r) {
        int row = m0 + wm * 64 + mf * 16 + (lane >> 4) * 4 + r;
        Outp[(size_t)row * 512 + o] = acc[mf][nf][r];
      }
    }
}

// ---------------------------------------------------------------- k_S4
// Spart[bid][m][n] = sum_{x in [x0,x0+16), y} bf16(k[m,cx]*v[m,k2y]) * bf16(Ano[c,k2,x,y,n])
// grid 256 = ck2(64) x xt(4). 256 thr / 4 waves; wave w owns m-rows w*64..+64.
// 2-deep register pipeline: named batches ra/rb (8 float4 each, uniform count),
// ONE barrier per x-step. Swizzles identical to round 7 (verified).
__global__ __launch_bounds__(256) void k_S4(const float* __restrict__ kw,
                                            const float* __restrict__ vw,
                                            const float* __restrict__ Ano,
                                            float* __restrict__ Spart) {
  __shared__ float ksl[16 * 256];                     // 16 KB  [xi][m]
  __shared__ unsigned vslw[256 * 32];                 // 32 KB
  __shared__ __align__(16) unsigned Bp[2][112 * 32];  // 28 KB dbuf
  const int bid = blockIdx.x;  // 256
  const int ck2 = bid & 63, xt = bid >> 6;
  const int c = ck2 >> 3, k2 = ck2 & 7;
  const int x0 = xt * 16;
  const int tid = threadIdx.x;
  const int lane = tid & 63;
  const int w = tid >> 6;
  const int l15 = lane & 15, hig = lane >> 4;

  const float* slab = Ano + (size_t)c * ANO_C_STR + (size_t)k2 * ANO_K_STR + (size_t)x0 * ANO_X_STR;

  // ---- stage k slice [16 x][256 m]
  {
    const float* kp = kw + (size_t)tid * 512 + c * 64 + x0;
#pragma unroll
    for (int q = 0; q < 4; ++q) {
      float4 kv = ld4(kp + q * 4);
      ksl[(q * 4 + 0) * 256 + tid] = kv.x;
      ksl[(q * 4 + 1) * 256 + tid] = kv.y;
      ksl[(q * 4 + 2) * 256 + tid] = kv.z;
      ksl[(q * 4 + 3) * 256 + tid] = kv.w;
    }
  }
  // ---- stage v slice as packed bf16 pairs (coalesced f4 loads)
#pragma unroll
  for (int p = 0; p < 16; ++p) {
    int id = p * 256 + tid;
    int m = id >> 4, yq = id & 15;
    float4 v4 = ld4(vw + (size_t)m * 512 + k2 * 64 + yq * 4);
    unsigned sw = ((unsigned)m & 7u) << 2;
    int base = m * 32 + ((yq * 2) ^ (int)sw);
    vslw[base] = cvtpk(v4.x, v4.y);
    vslw[base + 1] = cvtpk(v4.z, v4.w);
  }

  // ---- B staging geometry: unit u = ypair*25 + nq (800 units); uniform 4 units/thread
  int goff[4];
  int iw[4][4];
  bool wvalid[4];
#pragma unroll
  for (int j = 0; j < 4; ++j) {
    int u = tid + 256 * j;
    wvalid[j] = (u < 800);
    if (u >= 800) u = 799;
    int yp = u / 25, nq = u - yp * 25;
    goff[j] = yp * 200 + nq * 4;
#pragma unroll
    for (int e = 0; e < 4; ++e) {
      int n = nq * 4 + e;
      int s2 = (n ^ (n >> 3)) & 7;
      iw[j][e] = n * 32 + (yp ^ (s2 << 2));
    }
  }

  f32x4 acc[4][7];
#pragma unroll
  for (int mf = 0; mf < 4; ++mf)
#pragma unroll
    for (int nf = 0; nf < 7; ++nf) acc[mf][nf] = (f32x4)(0.f);

  // named register batches (2-deep pipeline)
  float4 ra0[4], ra1[4], rb0[4], rb1[4];

#define LOADB(R0, R1, xx)                                     \
  {                                                           \
    const float* px_ = slab + (size_t)(xx)*ANO_X_STR;         \
    _Pragma("unroll") for (int j = 0; j < 4; ++j) {           \
      R0[j] = ld4(px_ + goff[j]);                             \
      R1[j] = ld4(px_ + goff[j] + 100);                       \
    }                                                         \
  }

#define WRITEB(BUF, R0, R1)                                   \
  {                                                           \
    unsigned* bp_ = &Bp[BUF][0];                              \
    _Pragma("unroll") for (int j = 0; j < 4; ++j)             \
      if (wvalid[j]) {                                        \
        bp_[iw[j][0]] = cvtpk(R0[j].x, R1[j].x);              \
        bp_[iw[j][1]] = cvtpk(R0[j].y, R1[j].y);              \
        bp_[iw[j][2]] = cvtpk(R0[j].z, R1[j].z);              \
        bp_[iw[j][3]] = cvtpk(R0[j].w, R1[j].w);              \
      }                                                       \
  }

#define COMPUTE(BUF, xx)                                                              \
  {                                                                                   \
    const unsigned short* bp16_ = (const unsigned short*)&Bp[BUF][0];                 \
    _Pragma("unroll") for (int ks = 0; ks < 2; ++ks) {                                \
      int chunk = ks * 4 + hig;                                                       \
      bf16x8 bfr[7];                                                                  \
      _Pragma("unroll") for (int nf = 0; nf < 7; ++nf) {                              \
        int r = nf * 16 + l15;                                                        \
        int slot = chunk ^ ((r ^ (r >> 3)) & 7);                                      \
        bfr[nf] = *(const bf16x8*)&bp16_[r * 64 + slot * 8];                          \
      }                                                                               \
      _Pragma("unroll") for (int mf = 0; mf < 4; ++mf) {                              \
        int m = w * 64 + mf * 16 + l15;                                               \
        float kx = ksl[(xx)*256 + m];                                                 \
        int slot = chunk ^ (m & 7);                                                   \
        const unsigned* vp = &vslw[m * 32 + slot * 4];                                \
        unsigned v0 = vp[0], v1 = vp[1], v2 = vp[2], v3 = vp[3];                      \
        union { unsigned u[4]; bf16x8 v; } fu;                                        \
        fu.u[0] = cvtpk(kx * bflo(v0), kx * bfhi(v0));                                \
        fu.u[1] = cvtpk(kx * bflo(v1), kx * bfhi(v1));                                \
        fu.u[2] = cvtpk(kx * bflo(v2), kx * bfhi(v2));                                \
        fu.u[3] = cvtpk(kx * bflo(v3), kx * bfhi(v3));                                \
        _Pragma("unroll") for (int nf = 0; nf < 7; ++nf)                              \
          acc[mf][nf] = __builtin_amdgcn_mfma_f32_16x16x32_bf16(fu.v, bfr[nf],        \
                                                                acc[mf][nf], 0, 0, 0);\
      }                                                                               \
    }                                                                                 \
  }

  LOADB(ra0, ra1, 0)
  LOADB(rb0, rb1, 1)

#pragma unroll 1
  for (int xx = 0; xx < 16; xx += 2) {
    WRITEB(0, ra0, ra1)
    if (xx + 2 < 16) LOADB(ra0, ra1, xx + 2)
    __syncthreads();
    COMPUTE(0, xx)
    WRITEB(1, rb0, rb1)
    if (xx + 3 < 16) LOADB(rb0, rb1, xx + 3)
    __syncthreads();
    COMPUTE(1, xx + 1)
  }

  float* sp = Spart + (size_t)bid * 25600;
#pragma unroll
  for (int mf = 0; mf < 4; ++mf)
#pragma unroll
    for (int nf = 0; nf < 7; ++nf) {
      int n = nf * 16 + l15;
      if (n < 100) {
#pragma unroll
        for (int rr = 0; rr < 4; ++rr) {
          int m = w * 64 + mf * 16 + hig * 4 + rr;
          sp[(size_t)m * 100 + n] = acc[mf][nf][rr];
        }
      }
    }
#undef LOADB
#undef WRITEB
#undef COMPUTE
}

// ---------------------------------------------------------------- k_Sred
__global__ __launch_bounds__(512) void k_Sred(const float* __restrict__ Spart,
                                              float* __restrict__ S) {
  __shared__ float red[512];
  const int m = blockIdx.x;
  const int tid = threadIdx.x;
  const int q = tid >> 7, n = tid & 127;
  float acc = 0.f;
  if (n < 100) {
    const float* p = Spart + (size_t)q * 64 * 25600 + (size_t)m * 100 + n;
#pragma unroll 8
    for (int s = 0; s < 64; ++s) acc += p[(size_t)s * 25600];
  }
  red[tid] = acc;
  __syncthreads();
  if (tid < 100)
    S[m * 100 + tid] = red[tid] + red[128 + tid] + red[256 + tid] + red[384 + tid];
}

// ---------------------------------------------------------------- k_scan
__global__ __launch_bounds__(1024) void k_scan(const float* __restrict__ Ann,
                                               const float* __restrict__ Sg,
                                               float* __restrict__ ug) {
  __shared__ float Abuf[10000];
  __shared__ float s_s[800];
  __shared__ float u_s[800];
  __shared__ float red[16];
  __shared__ float gmax_s;
  const int tid = threadIdx.x;

  float lmax0 = 0.f;
  for (int f = tid; f < 10000; f += 1024) {
    float a = Ann[f];
    Abuf[f] = a;
    lmax0 = fmaxf(lmax0, fabsf(a));
  }
  for (int f = tid; f < 800; f += 1024) {
    int bp = f / 100, n = f - bp * 100;
    u_s[f] = Sg[(bp * 32 + 30) * 100 + n];
  }
#pragma unroll
  for (int off = 32; off > 0; off >>= 1) lmax0 = fmaxf(lmax0, __shfl_down(lmax0, off, 64));
  if ((tid & 63) == 0) red[tid >> 6] = lmax0;
  __syncthreads();
  if (tid == 0) {
    float mx = 0.f;
    for (int wv = 0; wv < 16; ++wv) mx = fmaxf(mx, red[wv]);
    gmax_s = mx;
  }
  const int ri = tid / 25;
  const int cj = tid - ri * 25;
  const bool sqact = (tid < 625);
  __syncthreads();

  for (int i = 0; i < 30; ++i) {
    const int t = 29 - i;
    for (int f = tid; f < 800; f += 1024) {
      int bp = f / 100, n = f - bp * 100;
      s_s[f] = Sg[(bp * 32 + t) * 100 + n];
    }
    __syncthreads();
    if (tid < 800) {
      int bp = tid / 100, n = tid - bp * 100;
      const float* Ar = &Abuf[n * 100];
      const float* sr = &s_s[bp * 100];
      float a0 = 0.f;
#pragma unroll
      for (int mm = 0; mm < 100; mm += 4) {
        float4 a4 = ld4(Ar + mm);
        float4 s4 = ld4(sr + mm);
        a0 += a4.x * s4.x + a4.y * s4.y + a4.z * s4.z + a4.w * s4.w;
      }
      u_s[tid] += a0;
    }
    if (i == 29) break;
    if (gmax_s < 1e-6f) break;

    float acc2[4][4];
    float lmax = 0.f;
    if (sqact) {
#pragma unroll
      for (int a = 0; a < 4; ++a)
#pragma unroll
        for (int b = 0; b < 4; ++b) acc2[a][b] = 0.f;
      for (int mm = 0; mm < 100; mm += 4) {
        float av[4][4], bv[4][4];
#pragma unroll
        for (int ii = 0; ii < 4; ++ii)
          *(float4*)&av[ii][0] = ld4(&Abuf[(ri * 4 + ii) * 100 + mm]);
#pragma unroll
        for (int mi = 0; mi < 4; ++mi)
          *(float4*)&bv[mi][0] = ld4(&Abuf[(mm + mi) * 100 + cj * 4]);
#pragma unroll
        for (int ii = 0; ii < 4; ++ii)
#pragma unroll
          for (int mi = 0; mi < 4; ++mi)
#pragma unroll
            for (int qq = 0; qq < 4; ++qq) acc2[ii][qq] += av[ii][mi] * bv[mi][qq];
      }
    }
    __syncthreads();
    if (sqact) {
#pragma unroll
      for (int ii = 0; ii < 4; ++ii) {
        float4 wv = make_float4(acc2[ii][0], acc2[ii][1], acc2[ii][2], acc2[ii][3]);
        *(float4*)&Abuf[(ri * 4 + ii) * 100 + cj * 4] = wv;
        lmax = fmaxf(lmax, fmaxf(fmaxf(fabsf(wv.x), fabsf(wv.y)), fmaxf(fabsf(wv.z), fabsf(wv.w))));
      }
    }
#pragma unroll
    for (int off = 32; off > 0; off >>= 1) lmax = fmaxf(lmax, __shfl_down(lmax, off, 64));
    if ((tid & 63) == 0) red[tid >> 6] = lmax;
    __syncthreads();
    if (tid == 0) {
      float mx = 0.f;
      for (int wv = 0; wv < 16; ++wv) mx = fmaxf(mx, red[wv]);
      gmax_s = mx;
    }
    __syncthreads();
  }
  __syncthreads();
  for (int f = tid; f < 800; f += 1024) ug[f] = u_s[f];
}

// ---------------------------------------------------------------- k_h
__global__ __launch_bounds__(256) void k_h(const float* __restrict__ Aon,
                                           const float* __restrict__ Aoo,
                                           const float* __restrict__ kw,
                                           const float* __restrict__ vw,
                                           const float* __restrict__ ug,
                                           float* __restrict__ h) {
  __shared__ float aon_s[6400];
  __shared__ float uT[100 * 8];
  __shared__ float aoo_s[64];
  __shared__ float kl_s[8];
  __shared__ float vl_s[8 * 64];
  __shared__ float part[4 * 64 * 8];
  const int bid = blockIdx.x;  // (a*8+b)*64+g
  const int g = bid & 63, b = (bid >> 6) & 7, a = bid >> 9;
  const int tid = threadIdx.x;

  {
    const float* ab = Aon + (size_t)bid * 6400;
#pragma unroll
    for (int p = 0; p < 7; ++p) {
      int id = p * 256 + tid;
      if (id < 1600) *(float4*)&aon_s[id * 4] = ld4(ab + (size_t)id * 4);
    }
  }
  for (int f = tid; f < 800; f += 256) {
    int n = f >> 3, bp = f & 7;
    uT[f] = ug[bp * 100 + n];
  }
  if (tid < 64) aoo_s[tid] = Aoo[(size_t)bid * 64 + tid];
  if (tid < 8) kl_s[tid] = kw[(size_t)(tid * 32 + 31) * 512 + a * 64 + g];
  for (int f = tid; f < 512; f += 256) {
    int bp = f >> 6, d = f & 63;
    vl_s[f] = vw[(size_t)(bp * 32 + 31) * 512 + b * 64 + d];
  }
  __syncthreads();

  const int ng = tid & 3, d = tid >> 2;
  const float* basep = &aon_s[d * 100 + ng * 25];
  float acc8[8];
#pragma unroll
  for (int bb = 0; bb < 8; ++bb) acc8[bb] = 0.f;
#pragma unroll
  for (int q = 0; q < 25; ++q) {
    int n = ng * 25 + q;
    float av = basep[q];
    float4 u0 = ld4(&uT[n * 8]);
    float4 u1 = ld4(&uT[n * 8 + 4]);
    acc8[0] += av * u0.x; acc8[1] += av * u0.y; acc8[2] += av * u0.z; acc8[3] += av * u0.w;
    acc8[4] += av * u1.x; acc8[5] += av * u1.y; acc8[6] += av * u1.z; acc8[7] += av * u1.w;
  }
  {
    float* pp = &part[(ng * 64 + d) * 8];
    *(float4*)pp = make_float4(acc8[0], acc8[1], acc8[2], acc8[3]);
    *(float4*)(pp + 4) = make_float4(acc8[4], acc8[5], acc8[6], acc8[7]);
  }
  __syncthreads();
  for (int o = tid; o < 512; o += 256) {
    int bp = o >> 6, d2 = o & 63;
    float s = aoo_s[d2] * kl_s[bp] * vl_s[bp * 64 + d2];
#pragma unroll
    for (int n2 = 0; n2 < 4; ++n2) s += part[(n2 * 64 + d2) * 8 + bp];
    h[(size_t)bp * 262144 + (size_t)bid * 64 + d2] = s;
  }
}

// ---------------------------------------------------------------- k_y
__global__ __launch_bounds__(256) void k_y(const float* __restrict__ qw,
                                           const float* __restrict__ h,
                                           float* __restrict__ out) {
  __shared__ float qT[32 * 32];
  __shared__ float Hs[32 * 64];
  const int bid = blockIdx.x;  // bp*8 + b
  const int bp = bid >> 3, b = bid & 7;
  const int tid = threadIdx.x;
  const int r2 = tid >> 4, c2 = tid & 15;
  const size_t hbase = (size_t)bp * 262144 + (size_t)b * 4096;
  float acc[2][4];
#pragma unroll
  for (int i = 0; i < 2; ++i)
#pragma unroll
    for (int q = 0; q < 4; ++q) acc[i][q] = 0.f;

  for (int kc = 0; kc < 512; kc += 32) {
    {
      int t = tid & 31, kq = tid >> 5;
      float4 qv = ld4(qw + (size_t)(bp * 32 + t) * 512 + kc + kq * 4);
      qT[(kq * 4 + 0) * 32 + t] = qv.x;
      qT[(kq * 4 + 1) * 32 + t] = qv.y;
      qT[(kq * 4 + 2) * 32 + t] = qv.z;
      qT[(kq * 4 + 3) * 32 + t] = qv.w;
    }
#pragma unroll
    for (int i2 = 0; i2 < 2; ++i2) {
      int fid = i2 * 256 + tid;
      int kk = fid >> 4, xq = (fid & 15) * 4;
      int row = kc + kk;
      int A = row >> 6, G = row & 63;
      float4 hv = ld4(h + hbase + (size_t)A * 32768 + (size_t)G * 64 + xq);
      *(float4*)&Hs[kk * 64 + xq] = hv;
    }
    __syncthreads();
#pragma unroll
    for (int kk = 0; kk < 32; ++kk) {
      float2 q2 = *(const float2*)&qT[kk * 32 + r2 * 2];
      float4 h4 = ld4(&Hs[kk * 64 + c2 * 4]);
      acc[0][0] += q2.x * h4.x; acc[0][1] += q2.x * h4.y; acc[0][2] += q2.x * h4.z; acc[0][3] += q2.x * h4.w;
      acc[1][0] += q2.y * h4.x; acc[1][1] += q2.y * h4.y; acc[1][2] += q2.y * h4.z; acc[1][3] += q2.y * h4.w;
    }
    __syncthreads();
  }
#pragma unroll
  for (int i = 0; i < 2; ++i) {
    float4 v = make_float4(acc[i][0], acc[i][1], acc[i][2], acc[i][3]);
    *(float4*)&out[(size_t)(bp * 32 + r2 * 2 + i) * 512 + b * 64 + c2 * 4] = v;
  }
}

// ---------------------------------------------------------------- launch
extern "C" void kernel_launch(void* const* d_in, const int* in_sizes, int n_in,
                              void* d_out, int out_size, void* d_ws, size_t ws_size,
                              hipStream_t stream) {
  const float* x   = (const float*)d_in[0];
  const float* K   = (const float*)d_in[1];
  const float* Q   = (const float*)d_in[2];
  const float* V   = (const float*)d_in[3];
  const float* Aoo = (const float*)d_in[4];
  const float* Ann = (const float*)d_in[5];
  const float* Aon = (const float*)d_in[6];
  const float* Ano = (const float*)d_in[7];
  float* out = (float*)d_out;

  float* ws = (float*)d_ws;
  float* kw  = ws;                                          // 131072
  float* qw  = kw + 131072;                                 // 131072
  float* vw  = qw + 131072;                                 // 131072
  float* S   = ws + 458752;                                 // 25600
  float* u   = S + 25600;                                   // 800
  unsigned short* A2  = (unsigned short*)(ws + 485152);     // 393216 u16
  unsigned short* Bw  = (unsigned short*)(ws + 681760);     // 2359296 u16
  float* h     = ws + 1861408;                              // 2097152
  float* Spart = ws + 3958560;                              // 6553600 (26.2 MB)

  k_prep<<<dim3(256), dim3(256), 0, stream>>>(x, A2);
  k_cvtW<<<dim3(1536), dim3(128), 0, stream>>>(K, Q, V, Bw);
  k_kqv3<<<dim3(24), dim3(256), 0, stream>>>(A2, Bw, kw);
  k_S4<<<dim3(256), dim3(256), 0, stream>>>(kw, vw, Ano, Spart);
  k_Sred<<<dim3(256), dim3(512), 0, stream>>>(Spart, S);
  k_scan<<<dim3(1), dim3(1024), 0, stream>>>(Ann, S, u);
  k_h<<<dim3(4096), dim3(256), 0, stream>>>(Aon, Aoo, kw, vw, u, h);
  k_y<<<dim3(64), dim3(256), 0, stream>>>(qw, h, out);
}

// Round 9
// 185.166 us; speedup vs baseline: 1.0460x; 1.0000x over previous
//
#include <hip/hip_runtime.h>

// GateLoopOperator, MI355X. Round 9:
//  - k_h2: streaming rewrite of k_h. 256 blocks = 64 (a,b) x 4 g-quarters; each block
//    pumps 16 Aon panels (64d x 100n f32) through dbuf LDS with a 2-deep register
//    pipeline (k_S4 recipe). Pad-101 rows -> 2-way-free LDS reads; u-reads are
//    wave-uniform broadcasts. HBM-bound by construction.
//
// Pipeline:
//  k_prep : A2[m][1536] bf16 = [hi(xp) | hi(xp) | lo(xp)]
//  k_cvtW : Bw[j][1536] bf16 = [hi(W) | lo | hi] (pre-permuted rows)
//  k_kqv3 : k/q/v f32 = A2 @ Bw^T (split-bf16 MFMA => f32 quality)
//  k_S4   : Spart[(xt,ck2)][m][n] = sum_{x,y} bf16(k v) * bf16(Ano) (2-deep pipeline)
//  k_Sred : S[m][n] = sum over 256 slabs
//  k_scan : u[bp,n] = S[bp,30] + sum_i Ann^(2^i) @ S[bp,29-i] (early-exit)
//  k_h2   : h = Aoo*k_last*v_last + Aon . u   (streaming, dbuf)
//  k_y    : y = q . h

#define ANO_C_STR 3276800
#define ANO_K_STR 409600
#define ANO_X_STR 6400

typedef __attribute__((ext_vector_type(8))) short bf16x8;
typedef __attribute__((ext_vector_type(4))) float f32x4;
typedef __attribute__((ext_vector_type(4))) unsigned short u16x4;

__device__ __forceinline__ float4 ld4(const float* p) { return *(const float4*)p; }

__device__ __forceinline__ unsigned short f2bf(float f) {  // RNE
  unsigned u = __float_as_uint(f);
  unsigned r = (u + 0x7fffu + ((u >> 16) & 1u)) >> 16;
  return (unsigned short)r;
}
__device__ __forceinline__ float bf2f(unsigned short b) {
  return __uint_as_float(((unsigned)b) << 16);
}
// 2 f32 -> u32 of 2 bf16 (lo -> low half). Used identically on A and B.
__device__ __forceinline__ unsigned cvtpk(float lo, float hi) {
  unsigned r;
  asm("v_cvt_pk_bf16_f32 %0, %1, %2" : "=v"(r) : "v"(lo), "v"(hi));
  return r;
}
__device__ __forceinline__ float bflo(unsigned u) { return __uint_as_float(u << 16); }
__device__ __forceinline__ float bfhi(unsigned u) { return __uint_as_float(u & 0xffff0000u); }

// ---------------------------------------------------------------- k_prep
__global__ __launch_bounds__(256) void k_prep(const float* __restrict__ X,
                                              unsigned short* __restrict__ A2) {
  __shared__ float xs[512];
  const int m = blockIdx.x;
  const int tid = threadIdx.x;
  for (int f = tid; f < 512; f += 256) xs[f] = X[m * 512 + f];
  __syncthreads();
  for (int f = tid; f < 512; f += 256) {
    float v = xs[((f & 7) << 6) | (f >> 3)];
    unsigned short hi = f2bf(v);
    unsigned short lo = f2bf(v - bf2f(hi));
    A2[(size_t)m * 1536 + f] = hi;
    A2[(size_t)m * 1536 + 512 + f] = hi;
    A2[(size_t)m * 1536 + 1024 + f] = lo;
  }
}

// ---------------------------------------------------------------- k_cvtW
__global__ __launch_bounds__(128) void k_cvtW(const float* __restrict__ Km,
                                              const float* __restrict__ Qm,
                                              const float* __restrict__ Vm,
                                              unsigned short* __restrict__ Bw) {
  const int j = blockIdx.x;  // mat*512 + o
  const int mat = j >> 9, o = j & 511;
  const int r = ((o & 63) << 3) | (o >> 6);
  const float* W = ((mat == 0) ? Km : ((mat == 1) ? Qm : Vm)) + (size_t)r * 512;
  const int tid = threadIdx.x;
  float4 v = ld4(W + tid * 4);
  u16x4 hi, lo;
  float vv[4] = {v.x, v.y, v.z, v.w};
#pragma unroll
  for (int e = 0; e < 4; ++e) {
    hi[e] = f2bf(vv[e]);
    lo[e] = f2bf(vv[e] - bf2f(hi[e]));
  }
  *(u16x4*)&Bw[(size_t)j * 1536 + tid * 4] = hi;
  *(u16x4*)&Bw[(size_t)j * 1536 + 512 + tid * 4] = lo;
  *(u16x4*)&Bw[(size_t)j * 1536 + 1024 + tid * 4] = hi;
}

// ---------------------------------------------------------------- k_kqv3
__global__ __launch_bounds__(256) void k_kqv3(const unsigned short* __restrict__ A2,
                                              const unsigned short* __restrict__ Bw,
                                              float* __restrict__ kqvF) {
  __shared__ __align__(16) unsigned short Asm[128 * 64];
  __shared__ __align__(16) unsigned short Bsm[128 * 64];
  const int bid = blockIdx.x;  // 24
  const int mt = bid & 1, jt = bid >> 1;
  const int m0 = mt * 128, j0 = jt * 128;
  const int tid = threadIdx.x;
  const int lane = tid & 63;
  const int w = tid >> 6;
  const int wm = w >> 1, wn = w & 1;

  f32x4 acc[4][4];
#pragma unroll
  for (int a = 0; a < 4; ++a)
#pragma unroll
    for (int b = 0; b < 4; ++b) acc[a][b] = (f32x4)(0.f);

  for (int kc = 0; kc < 1536; kc += 64) {
#pragma unroll
    for (int cch = 0; cch < 4; ++cch) {
      int sid = cch * 256 + tid;
      int r = sid >> 3, c8 = sid & 7;
      int srcc = c8 ^ (r & 7);
      const unsigned short* ga = A2 + (size_t)(m0 + r) * 1536 + kc + srcc * 8;
      __builtin_amdgcn_global_load_lds((const __attribute__((address_space(1))) unsigned int*)ga,
                                       (__attribute__((address_space(3))) unsigned int*)(&Asm[sid * 8]),
                                       16, 0, 0);
      const unsigned short* gb = Bw + (size_t)(j0 + r) * 1536 + kc + srcc * 8;
      __builtin_amdgcn_global_load_lds((const __attribute__((address_space(1))) unsigned int*)gb,
                                       (__attribute__((address_space(3))) unsigned int*)(&Bsm[sid * 8]),
                                       16, 0, 0);
    }
    __syncthreads();
#pragma unroll
    for (int ks = 0; ks < 2; ++ks) {
      bf16x8 af[4], bfr[4];
#pragma unroll
      for (int mf = 0; mf < 4; ++mf) {
        int r = wm * 64 + mf * 16 + (lane & 15);
        int slot = (ks * 4 + (lane >> 4)) ^ (r & 7);
        af[mf] = *(const bf16x8*)&Asm[r * 64 + slot * 8];
      }
#pragma unroll
      for (int nf = 0; nf < 4; ++nf) {
        int r = wn * 64 + nf * 16 + (lane & 15);
        int slot = (ks * 4 + (lane >> 4)) ^ (r & 7);
        bfr[nf] = *(const bf16x8*)&Bsm[r * 64 + slot * 8];
      }
#pragma unroll
      for (int mf = 0; mf < 4; ++mf)
#pragma unroll
        for (int nf = 0; nf < 4; ++nf)
          acc[mf][nf] = __builtin_amdgcn_mfma_f32_16x16x32_bf16(af[mf], bfr[nf], acc[mf][nf], 0, 0, 0);
    }
    __syncthreads();
  }
#pragma unroll
  for (int mf = 0; mf < 4; ++mf)
#pragma unroll
    for (int nf = 0; nf < 4; ++nf) {
      int col = j0 + wn * 64 + nf * 16 + (lane & 15);
      int mat = col >> 9, o = col & 511;
      float* Outp = kqvF + (size_t)mat * 131072;
#pragma unroll
      for (int r = 0; r < 4; ++r) {
        int row = m0 + wm * 64 + mf * 16 + (lane >> 4) * 4 + r;
        Outp[(size_t)row * 512 + o] = acc[mf][nf][r];
      }
    }
}

// ---------------------------------------------------------------- k_S4
__global__ __launch_bounds__(256) void k_S4(const float* __restrict__ kw,
                                            const float* __restrict__ vw,
                                            const float* __restrict__ Ano,
                                            float* __restrict__ Spart) {
  __shared__ float ksl[16 * 256];
  __shared__ unsigned vslw[256 * 32];
  __shared__ __align__(16) unsigned Bp[2][112 * 32];
  const int bid = blockIdx.x;  // 256
  const int ck2 = bid & 63, xt = bid >> 6;
  const int c = ck2 >> 3, k2 = ck2 & 7;
  const int x0 = xt * 16;
  const int tid = threadIdx.x;
  const int lane = tid & 63;
  const int w = tid >> 6;
  const int l15 = lane & 15, hig = lane >> 4;

  const float* slab = Ano + (size_t)c * ANO_C_STR + (size_t)k2 * ANO_K_STR + (size_t)x0 * ANO_X_STR;

  {
    const float* kp = kw + (size_t)tid * 512 + c * 64 + x0;
#pragma unroll
    for (int q = 0; q < 4; ++q) {
      float4 kv = ld4(kp + q * 4);
      ksl[(q * 4 + 0) * 256 + tid] = kv.x;
      ksl[(q * 4 + 1) * 256 + tid] = kv.y;
      ksl[(q * 4 + 2) * 256 + tid] = kv.z;
      ksl[(q * 4 + 3) * 256 + tid] = kv.w;
    }
  }
#pragma unroll
  for (int p = 0; p < 16; ++p) {
    int id = p * 256 + tid;
    int m = id >> 4, yq = id & 15;
    float4 v4 = ld4(vw + (size_t)m * 512 + k2 * 64 + yq * 4);
    unsigned sw = ((unsigned)m & 7u) << 2;
    int base = m * 32 + ((yq * 2) ^ (int)sw);
    vslw[base] = cvtpk(v4.x, v4.y);
    vslw[base + 1] = cvtpk(v4.z, v4.w);
  }

  int goff[4];
  int iw[4][4];
  bool wvalid[4];
#pragma unroll
  for (int j = 0; j < 4; ++j) {
    int u = tid + 256 * j;
    wvalid[j] = (u < 800);
    if (u >= 800) u = 799;
    int yp = u / 25, nq = u - yp * 25;
    goff[j] = yp * 200 + nq * 4;
#pragma unroll
    for (int e = 0; e < 4; ++e) {
      int n = nq * 4 + e;
      int s2 = (n ^ (n >> 3)) & 7;
      iw[j][e] = n * 32 + (yp ^ (s2 << 2));
    }
  }

  f32x4 acc[4][7];
#pragma unroll
  for (int mf = 0; mf < 4; ++mf)
#pragma unroll
    for (int nf = 0; nf < 7; ++nf) acc[mf][nf] = (f32x4)(0.f);

  float4 ra0[4], ra1[4], rb0[4], rb1[4];

#define LOADB(R0, R1, xx)                                     \
  {                                                           \
    const float* px_ = slab + (size_t)(xx)*ANO_X_STR;         \
    _Pragma("unroll") for (int j = 0; j < 4; ++j) {           \
      R0[j] = ld4(px_ + goff[j]);                             \
      R1[j] = ld4(px_ + goff[j] + 100);                       \
    }                                                         \
  }

#define WRITEB(BUF, R0, R1)                                   \
  {                                                           \
    unsigned* bp_ = &Bp[BUF][0];                              \
    _Pragma("unroll") for (int j = 0; j < 4; ++j)             \
      if (wvalid[j]) {                                        \
        bp_[iw[j][0]] = cvtpk(R0[j].x, R1[j].x);              \
        bp_[iw[j][1]] = cvtpk(R0[j].y, R1[j].y);              \
        bp_[iw[j][2]] = cvtpk(R0[j].z, R1[j].z);              \
        bp_[iw[j][3]] = cvtpk(R0[j].w, R1[j].w);              \
      }                                                       \
  }

#define COMPUTE(BUF, xx)                                                              \
  {                                                                                   \
    const unsigned short* bp16_ = (const unsigned short*)&Bp[BUF][0];                 \
    _Pragma("unroll") for (int ks = 0; ks < 2; ++ks) {                                \
      int chunk = ks * 4 + hig;                                                       \
      bf16x8 bfr[7];                                                                  \
      _Pragma("unroll") for (int nf = 0; nf < 7; ++nf) {                              \
        int r = nf * 16 + l15;                                                        \
        int slot = chunk ^ ((r ^ (r >> 3)) & 7);                                      \
        bfr[nf] = *(const bf16x8*)&bp16_[r * 64 + slot * 8];                          \
      }                                                                               \
      _Pragma("unroll") for (int mf = 0; mf < 4; ++mf) {                              \
        int m = w * 64 + mf * 16 + l15;                                               \
        float kx = ksl[(xx)*256 + m];                                                 \
        int slot = chunk ^ (m & 7);                                                   \
        const unsigned* vp = &vslw[m * 32 + slot * 4];                                \
        unsigned v0 = vp[0], v1 = vp[1], v2 = vp[2], v3 = vp[3];                      \
        union { unsigned u[4]; bf16x8 v; } fu;                                        \
        fu.u[0] = cvtpk(kx * bflo(v0), kx * bfhi(v0));                                \
        fu.u[1] = cvtpk(kx * bflo(v1), kx * bfhi(v1));                                \
        fu.u[2] = cvtpk(kx * bflo(v2), kx * bfhi(v2));                                \
        fu.u[3] = cvtpk(kx * bflo(v3), kx * bfhi(v3));                                \
        _Pragma("unroll") for (int nf = 0; nf < 7; ++nf)                              \
          acc[mf][nf] = __builtin_amdgcn_mfma_f32_16x16x32_bf16(fu.v, bfr[nf],        \
                                                                acc[mf][nf], 0, 0, 0);\
      }                                                                               \
    }                                                                                 \
  }

  LOADB(ra0, ra1, 0)
  LOADB(rb0, rb1, 1)

#pragma unroll 1
  for (int xx = 0; xx < 16; xx += 2) {
    WRITEB(0, ra0, ra1)
    if (xx + 2 < 16) LOADB(ra0, ra1, xx + 2)
    __syncthreads();
    COMPUTE(0, xx)
    WRITEB(1, rb0, rb1)
    if (xx + 3 < 16) LOADB(rb0, rb1, xx + 3)
    __syncthreads();
    COMPUTE(1, xx + 1)
  }

  float* sp = Spart + (size_t)bid * 25600;
#pragma unroll
  for (int mf = 0; mf < 4; ++mf)
#pragma unroll
    for (int nf = 0; nf < 7; ++nf) {
      int n = nf * 16 + l15;
      if (n < 100) {
#pragma unroll
        for (int rr = 0; rr < 4; ++rr) {
          int m = w * 64 + mf * 16 + hig * 4 + rr;
          sp[(size_t)m * 100 + n] = acc[mf][nf][rr];
        }
      }
    }
#undef LOADB
#undef WRITEB
#undef COMPUTE
}

// ---------------------------------------------------------------- k_Sred
__global__ __launch_bounds__(512) void k_Sred(const float* __restrict__ Spart,
                                              float* __restrict__ S) {
  __shared__ float red[512];
  const int m = blockIdx.x;
  const int tid = threadIdx.x;
  const int q = tid >> 7, n = tid & 127;
  float acc = 0.f;
  if (n < 100) {
    const float* p = Spart + (size_t)q * 64 * 25600 + (size_t)m * 100 + n;
#pragma unroll 8
    for (int s = 0; s < 64; ++s) acc += p[(size_t)s * 25600];
  }
  red[tid] = acc;
  __syncthreads();
  if (tid < 100)
    S[m * 100 + tid] = red[tid] + red[128 + tid] + red[256 + tid] + red[384 + tid];
}

// ---------------------------------------------------------------- k_scan
__global__ __launch_bounds__(1024) void k_scan(const float* __restrict__ Ann,
                                               const float* __restrict__ Sg,
                                               float* __restrict__ ug) {
  __shared__ float Abuf[10000];
  __shared__ float s_s[800];
  __shared__ float u_s[800];
  __shared__ float red[16];
  __shared__ float gmax_s;
  const int tid = threadIdx.x;

  float lmax0 = 0.f;
  for (int f = tid; f < 10000; f += 1024) {
    float a = Ann[f];
    Abuf[f] = a;
    lmax0 = fmaxf(lmax0, fabsf(a));
  }
  for (int f = tid; f < 800; f += 1024) {
    int bp = f / 100, n = f - bp * 100;
    u_s[f] = Sg[(bp * 32 + 30) * 100 + n];
  }
#pragma unroll
  for (int off = 32; off > 0; off >>= 1) lmax0 = fmaxf(lmax0, __shfl_down(lmax0, off, 64));
  if ((tid & 63) == 0) red[tid >> 6] = lmax0;
  __syncthreads();
  if (tid == 0) {
    float mx = 0.f;
    for (int wv = 0; wv < 16; ++wv) mx = fmaxf(mx, red[wv]);
    gmax_s = mx;
  }
  const int ri = tid / 25;
  const int cj = tid - ri * 25;
  const bool sqact = (tid < 625);
  __syncthreads();

  for (int i = 0; i < 30; ++i) {
    const int t = 29 - i;
    for (int f = tid; f < 800; f += 1024) {
      int bp = f / 100, n = f - bp * 100;
      s_s[f] = Sg[(bp * 32 + t) * 100 + n];
    }
    __syncthreads();
    if (tid < 800) {
      int bp = tid / 100, n = tid - bp * 100;
      const float* Ar = &Abuf[n * 100];
      const float* sr = &s_s[bp * 100];
      float a0 = 0.f;
#pragma unroll
      for (int mm = 0; mm < 100; mm += 4) {
        float4 a4 = ld4(Ar + mm);
        float4 s4 = ld4(sr + mm);
        a0 += a4.x * s4.x + a4.y * s4.y + a4.z * s4.z + a4.w * s4.w;
      }
      u_s[tid] += a0;
    }
    if (i == 29) break;
    if (gmax_s < 1e-6f) break;

    float acc2[4][4];
    float lmax = 0.f;
    if (sqact) {
#pragma unroll
      for (int a = 0; a < 4; ++a)
#pragma unroll
        for (int b = 0; b < 4; ++b) acc2[a][b] = 0.f;
      for (int mm = 0; mm < 100; mm += 4) {
        float av[4][4], bv[4][4];
#pragma unroll
        for (int ii = 0; ii < 4; ++ii)
          *(float4*)&av[ii][0] = ld4(&Abuf[(ri * 4 + ii) * 100 + mm]);
#pragma unroll
        for (int mi = 0; mi < 4; ++mi)
          *(float4*)&bv[mi][0] = ld4(&Abuf[(mm + mi) * 100 + cj * 4]);
#pragma unroll
        for (int ii = 0; ii < 4; ++ii)
#pragma unroll
          for (int mi = 0; mi < 4; ++mi)
#pragma unroll
            for (int qq = 0; qq < 4; ++qq) acc2[ii][qq] += av[ii][mi] * bv[mi][qq];
      }
    }
    __syncthreads();
    if (sqact) {
#pragma unroll
      for (int ii = 0; ii < 4; ++ii) {
        float4 wv = make_float4(acc2[ii][0], acc2[ii][1], acc2[ii][2], acc2[ii][3]);
        *(float4*)&Abuf[(ri * 4 + ii) * 100 + cj * 4] = wv;
        lmax = fmaxf(lmax, fmaxf(fmaxf(fabsf(wv.x), fabsf(wv.y)), fmaxf(fabsf(wv.z), fabsf(wv.w))));
      }
    }
#pragma unroll
    for (int off = 32; off > 0; off >>= 1) lmax = fmaxf(lmax, __shfl_down(lmax, off, 64));
    if ((tid & 63) == 0) red[tid >> 6] = lmax;
    __syncthreads();
    if (tid == 0) {
      float mx = 0.f;
      for (int wv = 0; wv < 16; ++wv) mx = fmaxf(mx, red[wv]);
      gmax_s = mx;
    }
    __syncthreads();
  }
  __syncthreads();
  for (int f = tid; f < 800; f += 1024) ug[f] = u_s[f];
}

// ---------------------------------------------------------------- k_h2
// h[bp, a,b,g,d] = Aoo[a,b,g,d]*k_last[bp,a,g]*v_last[bp,b,d] + sum_n Aon[a,b,g,d,n]*u[bp,n]
// grid 256 = ab(64) x gq(4); 16 g-panels per block, dbuf LDS + 2-deep reg pipeline.
// aonp rows padded to 101 -> read bank (5d+n)%32 = exactly 2 lanes/bank (free).
// u-reads wave-uniform (pp = wave id) -> broadcast.
__global__ __launch_bounds__(256) void k_h2(const float* __restrict__ Aon,
                                            const float* __restrict__ Aoo,
                                            const float* __restrict__ kw,
                                            const float* __restrict__ vw,
                                            const float* __restrict__ ug,
                                            float* __restrict__ h) {
  __shared__ float aonp[2][64 * 101];  // 51.7 KB
  __shared__ float uu[800];            // [n][bp]
  __shared__ float vl[512];            // [bp][d]
  __shared__ float kl[128];            // [bp][gi]
  __shared__ float aoo_s[1024];        // [gi][d]
  const int bid = blockIdx.x;  // 256
  const int ab = bid >> 2, gq = bid & 3;
  const int a = ab >> 3, b = ab & 7;
  const int g0 = gq * 16;
  const int tid = threadIdx.x;
  const int d = tid & 63;
  const int pp = tid >> 6;  // wave id -> bp pair {2pp, 2pp+1}

  // ---- small staging
  for (int f = tid; f < 800; f += 256) {
    int n = f >> 3, bp = f & 7;
    uu[f] = ug[bp * 100 + n];
  }
  for (int f = tid; f < 512; f += 256) {
    int bp = f >> 6, dd = f & 63;
    vl[f] = vw[(size_t)(bp * 32 + 31) * 512 + b * 64 + dd];
  }
  if (tid < 128) {
    int bp = tid >> 4, gi = tid & 15;
    kl[tid] = kw[(size_t)(bp * 32 + 31) * 512 + a * 64 + g0 + gi];
  }
  *(float4*)&aoo_s[tid * 4] = ld4(Aoo + ((size_t)ab * 64 + g0) * 64 + tid * 4);

  // ---- per-thread staging geometry: 1600 float4 per panel; thread owns fi = i*256+tid
  // (i<6) plus fi = 1536+tid for tid<64. LDS offsets precomputed (pad-101 remap).
  const bool w7 = (tid < 64);
  int woff[7][4];
#pragma unroll
  for (int i = 0; i < 7; ++i) {
    int fi = (i < 6) ? (i * 256 + tid) : (1536 + (tid & 63));
    int flat = fi * 4;
#pragma unroll
    for (int e = 0; e < 4; ++e) {
      int ff = flat + e;
      int dd = ff / 100;
      woff[i][e] = dd * 101 + (ff - dd * 100);
    }
  }

  const float* base0 = Aon + ((size_t)ab * 4096 + (size_t)g0 * 64) * 100;

  float4 rA[7], rB[7];

#define LOADH(R, gi)                                              \
  {                                                               \
    const float* pb_ = base0 + (size_t)(gi)*6400;                 \
    _Pragma("unroll") for (int i = 0; i < 6; ++i)                 \
        R[i] = ld4(pb_ + (i * 256 + tid) * 4);                    \
    if (w7) R[6] = ld4(pb_ + (1536 + tid) * 4);                   \
  }

#define WRITEH(BUF, R)                                            \
  {                                                               \
    float* ap_ = &aonp[BUF][0];                                   \
    _Pragma("unroll") for (int i = 0; i < 6; ++i) {               \
      ap_[woff[i][0]] = R[i].x;                                   \
      ap_[woff[i][1]] = R[i].y;                                   \
      ap_[woff[i][2]] = R[i].z;                                   \
      ap_[woff[i][3]] = R[i].w;                                   \
    }                                                             \
    if (w7) {                                                     \
      ap_[woff[6][0]] = R[6].x;                                   \
      ap_[woff[6][1]] = R[6].y;                                   \
      ap_[woff[6][2]] = R[6].z;                                   \
      ap_[woff[6][3]] = R[6].w;                                   \
    }                                                             \
  }

#define COMPUTEH(BUF, gi)                                         \
  {                                                               \
    const float* row_ = &aonp[BUF][d * 101];                      \
    float a0 = 0.f, a1 = 0.f, b0 = 0.f, b1 = 0.f;                 \
    _Pragma("unroll 10") for (int n = 0; n < 100; n += 2) {       \
      float x0 = row_[n], x1 = row_[n + 1];                       \
      float2 u0 = *(const float2*)&uu[n * 8 + pp * 2];            \
      float2 u1 = *(const float2*)&uu[(n + 1) * 8 + pp * 2];      \
      a0 += x0 * u0.x; a1 += x0 * u0.y;                           \
      b0 += x1 * u1.x; b1 += x1 * u1.y;                           \
    }                                                             \
    float acc0 = a0 + b0, acc1 = a1 + b1;                         \
    float av = aoo_s[(gi)*64 + d];                                \
    int bp0 = pp * 2, bp1 = pp * 2 + 1;                           \
    float h0 = av * kl[bp0 * 16 + (gi)] * vl[bp0 * 64 + d] + acc0;\
    float h1 = av * kl[bp1 * 16 + (gi)] * vl[bp1 * 64 + d] + acc1;\
    size_t ob_ = ((size_t)ab * 64 + g0 + (gi)) * 64 + d;          \
    h[(size_t)bp0 * 262144 + ob_] = h0;                           \
    h[(size_t)bp1 * 262144 + ob_] = h1;                           \
  }

  LOADH(rA, 0)
  LOADH(rB, 1)

#pragma unroll 1
  for (int gs = 0; gs < 16; gs += 2) {
    WRITEH(0, rA)
    if (gs + 2 < 16) LOADH(rA, gs + 2)
    __syncthreads();
    COMPUTEH(0, gs)
    __syncthreads();
    WRITEH(1, rB)
    if (gs + 3 < 16) LOADH(rB, gs + 3)
    __syncthreads();
    COMPUTEH(1, gs + 1)
    __syncthreads();
  }
#undef LOADH
#undef WRITEH
#undef COMPUTEH
}

// ---------------------------------------------------------------- k_y
__global__ __launch_bounds__(256) void k_y(const float* __restrict__ qw,
                                           const float* __restrict__ h,
                                           float* __restrict__ out) {
  __shared__ float qT[32 * 32];
  __shared__ float Hs[32 * 64];
  const int bid = blockIdx.x;  // bp*8 + b
  const int bp = bid >> 3, b = bid & 7;
  const int tid = threadIdx.x;
  const int r2 = tid >> 4, c2 = tid & 15;
  const size_t hbase = (size_t)bp * 262144 + (size_t)b * 4096;
  float acc[2][4];
#pragma unroll
  for (int i = 0; i < 2; ++i)
#pragma unroll
    for (int q = 0; q < 4; ++q) acc[i][q] = 0.f;

  for (int kc = 0; kc < 512; kc += 32) {
    {
      int t = tid & 31, kq = tid >> 5;
      float4 qv = ld4(qw + (size_t)(bp * 32 + t) * 512 + kc + kq * 4);
      qT[(kq * 4 + 0) * 32 + t] = qv.x;
      qT[(kq * 4 + 1) * 32 + t] = qv.y;
      qT[(kq * 4 + 2) * 32 + t] = qv.z;
      qT[(kq * 4 + 3) * 32 + t] = qv.w;
    }
#pragma unroll
    for (int i2 = 0; i2 < 2; ++i2) {
      int fid = i2 * 256 + tid;
      int kk = fid >> 4, xq = (fid & 15) * 4;
      int row = kc + kk;
      int A = row >> 6, G = row & 63;
      float4 hv = ld4(h + hbase + (size_t)A * 32768 + (size_t)G * 64 + xq);
      *(float4*)&Hs[kk * 64 + xq] = hv;
    }
    __syncthreads();
#pragma unroll
    for (int kk = 0; kk < 32; ++kk) {
      float2 q2 = *(const float2*)&qT[kk * 32 + r2 * 2];
      float4 h4 = ld4(&Hs[kk * 64 + c2 * 4]);
      acc[0][0] += q2.x * h4.x; acc[0][1] += q2.x * h4.y; acc[0][2] += q2.x * h4.z; acc[0][3] += q2.x * h4.w;
      acc[1][0] += q2.y * h4.x; acc[1][1] += q2.y * h4.y; acc[1][2] += q2.y * h4.z; acc[1][3] += q2.y * h4.w;
    }
    __syncthreads();
  }
#pragma unroll
  for (int i = 0; i < 2; ++i) {
    float4 v = make_float4(acc[i][0], acc[i][1], acc[i][2], acc[i][3]);
    *(float4*)&out[(size_t)(bp * 32 + r2 * 2 + i) * 512 + b * 64 + c2 * 4] = v;
  }
}

// ---------------------------------------------------------------- launch
extern "C" void kernel_launch(void* const* d_in, const int* in_sizes, int n_in,
                              void* d_out, int out_size, void* d_ws, size_t ws_size,
                              hipStream_t stream) {
  const float* x   = (const float*)d_in[0];
  const float* K   = (const float*)d_in[1];
  const float* Q   = (const float*)d_in[2];
  const float* V   = (const float*)d_in[3];
  const float* Aoo = (const float*)d_in[4];
  const float* Ann = (const float*)d_in[5];
  const float* Aon = (const float*)d_in[6];
  const float* Ano = (const float*)d_in[7];
  float* out = (float*)d_out;

  float* ws = (float*)d_ws;
  float* kw  = ws;                                          // 131072
  float* qw  = kw + 131072;                                 // 131072
  float* vw  = qw + 131072;                                 // 131072
  float* S   = ws + 458752;                                 // 25600
  float* u   = S + 25600;                                   // 800
  unsigned short* A2  = (unsigned short*)(ws + 485152);     // 393216 u16
  unsigned short* Bw  = (unsigned short*)(ws + 681760);     // 2359296 u16
  float* h     = ws + 1861408;                              // 2097152
  float* Spart = ws + 3958560;                              // 6553600 (26.2 MB)

  k_prep<<<dim3(256), dim3(256), 0, stream>>>(x, A2);
  k_cvtW<<<dim3(1536), dim3(128), 0, stream>>>(K, Q, V, Bw);
  k_kqv3<<<dim3(24), dim3(256), 0, stream>>>(A2, Bw, kw);
  k_S4<<<dim3(256), dim3(256), 0, stream>>>(kw, vw, Ano, Spart);
  k_Sred<<<dim3(256), dim3(512), 0, stream>>>(Spart, S);
  k_scan<<<dim3(1), dim3(1024), 0, stream>>>(Ann, S, u);
  k_h2<<<dim3(256), dim3(256), 0, stream>>>(Aon, Aoo, kw, vw, u, h);
  k_y<<<dim3(64), dim3(256), 0, stream>>>(qw, h, out);
}

// Round 10
// 161.328 us; speedup vs baseline: 1.2006x; 1.1478x over previous
//
#include <hip/hip_runtime.h>

// GateLoopOperator, MI355X. Round 10:
//  - k_h3: b128 LDS reads (pad-108), wave-uniform u broadcasts, float4 LDS writes,
//    2-deep pipeline with 2 barriers/2 panels, grid 512 -> 2 blocks/CU. HBM-bound.
//  - k_scan2: matrix squaring via MFMA (bf16 in, f32 acc) with chunk-XOR-swizzled
//    Ah/ATh buffers; matvec f32-exact for i=0 (global Ann), bf16 A for i>=1.
//
// Pipeline:
//  k_prep / k_cvtW / k_kqv3 : split-bf16 MFMA projections (f32 quality)
//  k_S4  : Spart = sum_{x,y} bf16(k v) * bf16(Ano)  (2-deep pipeline)
//  k_Sred: S = sum over 256 slabs
//  k_scan2: u[bp] = S[bp,30] + sum_i A^(2^i) S[bp,29-i]  (MFMA squaring, early-exit)
//  k_h3  : h = Aoo*k_last*v_last + Aon . u
//  k_y   : y = q . h

#define ANO_C_STR 3276800
#define ANO_K_STR 409600
#define ANO_X_STR 6400

typedef __attribute__((ext_vector_type(8))) short bf16x8;
typedef __attribute__((ext_vector_type(4))) float f32x4;
typedef __attribute__((ext_vector_type(4))) unsigned short u16x4;
typedef __attribute__((ext_vector_type(8))) unsigned short u16x8;

__device__ __forceinline__ float4 ld4(const float* p) { return *(const float4*)p; }

__device__ __forceinline__ unsigned short f2bf(float f) {  // RNE
  unsigned u = __float_as_uint(f);
  unsigned r = (u + 0x7fffu + ((u >> 16) & 1u)) >> 16;
  return (unsigned short)r;
}
__device__ __forceinline__ float bf2f(unsigned short b) {
  return __uint_as_float(((unsigned)b) << 16);
}
__device__ __forceinline__ unsigned cvtpk(float lo, float hi) {
  unsigned r;
  asm("v_cvt_pk_bf16_f32 %0, %1, %2" : "=v"(r) : "v"(lo), "v"(hi));
  return r;
}
__device__ __forceinline__ float bflo(unsigned u) { return __uint_as_float(u << 16); }
__device__ __forceinline__ float bfhi(unsigned u) { return __uint_as_float(u & 0xffff0000u); }

// ---------------------------------------------------------------- k_prep
__global__ __launch_bounds__(256) void k_prep(const float* __restrict__ X,
                                              unsigned short* __restrict__ A2) {
  __shared__ float xs[512];
  const int m = blockIdx.x;
  const int tid = threadIdx.x;
  for (int f = tid; f < 512; f += 256) xs[f] = X[m * 512 + f];
  __syncthreads();
  for (int f = tid; f < 512; f += 256) {
    float v = xs[((f & 7) << 6) | (f >> 3)];
    unsigned short hi = f2bf(v);
    unsigned short lo = f2bf(v - bf2f(hi));
    A2[(size_t)m * 1536 + f] = hi;
    A2[(size_t)m * 1536 + 512 + f] = hi;
    A2[(size_t)m * 1536 + 1024 + f] = lo;
  }
}

// ---------------------------------------------------------------- k_cvtW
__global__ __launch_bounds__(128) void k_cvtW(const float* __restrict__ Km,
                                              const float* __restrict__ Qm,
                                              const float* __restrict__ Vm,
                                              unsigned short* __restrict__ Bw) {
  const int j = blockIdx.x;  // mat*512 + o
  const int mat = j >> 9, o = j & 511;
  const int r = ((o & 63) << 3) | (o >> 6);
  const float* W = ((mat == 0) ? Km : ((mat == 1) ? Qm : Vm)) + (size_t)r * 512;
  const int tid = threadIdx.x;
  float4 v = ld4(W + tid * 4);
  u16x4 hi, lo;
  float vv[4] = {v.x, v.y, v.z, v.w};
#pragma unroll
  for (int e = 0; e < 4; ++e) {
    hi[e] = f2bf(vv[e]);
    lo[e] = f2bf(vv[e] - bf2f(hi[e]));
  }
  *(u16x4*)&Bw[(size_t)j * 1536 + tid * 4] = hi;
  *(u16x4*)&Bw[(size_t)j * 1536 + 512 + tid * 4] = lo;
  *(u16x4*)&Bw[(size_t)j * 1536 + 1024 + tid * 4] = hi;
}

// ---------------------------------------------------------------- k_kqv3
__global__ __launch_bounds__(256) void k_kqv3(const unsigned short* __restrict__ A2,
                                              const unsigned short* __restrict__ Bw,
                                              float* __restrict__ kqvF) {
  __shared__ __align__(16) unsigned short Asm[128 * 64];
  __shared__ __align__(16) unsigned short Bsm[128 * 64];
  const int bid = blockIdx.x;  // 24
  const int mt = bid & 1, jt = bid >> 1;
  const int m0 = mt * 128, j0 = jt * 128;
  const int tid = threadIdx.x;
  const int lane = tid & 63;
  const int w = tid >> 6;
  const int wm = w >> 1, wn = w & 1;

  f32x4 acc[4][4];
#pragma unroll
  for (int a = 0; a < 4; ++a)
#pragma unroll
    for (int b = 0; b < 4; ++b) acc[a][b] = (f32x4)(0.f);

  for (int kc = 0; kc < 1536; kc += 64) {
#pragma unroll
    for (int cch = 0; cch < 4; ++cch) {
      int sid = cch * 256 + tid;
      int r = sid >> 3, c8 = sid & 7;
      int srcc = c8 ^ (r & 7);
      const unsigned short* ga = A2 + (size_t)(m0 + r) * 1536 + kc + srcc * 8;
      __builtin_amdgcn_global_load_lds((const __attribute__((address_space(1))) unsigned int*)ga,
                                       (__attribute__((address_space(3))) unsigned int*)(&Asm[sid * 8]),
                                       16, 0, 0);
      const unsigned short* gb = Bw + (size_t)(j0 + r) * 1536 + kc + srcc * 8;
      __builtin_amdgcn_global_load_lds((const __attribute__((address_space(1))) unsigned int*)gb,
                                       (__attribute__((address_space(3))) unsigned int*)(&Bsm[sid * 8]),
                                       16, 0, 0);
    }
    __syncthreads();
#pragma unroll
    for (int ks = 0; ks < 2; ++ks) {
      bf16x8 af[4], bfr[4];
#pragma unroll
      for (int mf = 0; mf < 4; ++mf) {
        int r = wm * 64 + mf * 16 + (lane & 15);
        int slot = (ks * 4 + (lane >> 4)) ^ (r & 7);
        af[mf] = *(const bf16x8*)&Asm[r * 64 + slot * 8];
      }
#pragma unroll
      for (int nf = 0; nf < 4; ++nf) {
        int r = wn * 64 + nf * 16 + (lane & 15);
        int slot = (ks * 4 + (lane >> 4)) ^ (r & 7);
        bfr[nf] = *(const bf16x8*)&Bsm[r * 64 + slot * 8];
      }
#pragma unroll
      for (int mf = 0; mf < 4; ++mf)
#pragma unroll
        for (int nf = 0; nf < 4; ++nf)
          acc[mf][nf] = __builtin_amdgcn_mfma_f32_16x16x32_bf16(af[mf], bfr[nf], acc[mf][nf], 0, 0, 0);
    }
    __syncthreads();
  }
#pragma unroll
  for (int mf = 0; mf < 4; ++mf)
#pragma unroll
    for (int nf = 0; nf < 4; ++nf) {
      int col = j0 + wn * 64 + nf * 16 + (lane & 15);
      int mat = col >> 9, o = col & 511;
      float* Outp = kqvF + (size_t)mat * 131072;
#pragma unroll
      for (int r = 0; r < 4; ++r) {
        int row = m0 + wm * 64 + mf * 16 + (lane >> 4) * 4 + r;
        Outp[(size_t)row * 512 + o] = acc[mf][nf][r];
      }
    }
}

// ---------------------------------------------------------------- k_S4
__global__ __launch_bounds__(256) void k_S4(const float* __restrict__ kw,
                                            const float* __restrict__ vw,
                                            const float* __restrict__ Ano,
                                            float* __restrict__ Spart) {
  __shared__ float ksl[16 * 256];
  __shared__ unsigned vslw[256 * 32];
  __shared__ __align__(16) unsigned Bp[2][112 * 32];
  const int bid = blockIdx.x;  // 256
  const int ck2 = bid & 63, xt = bid >> 6;
  const int c = ck2 >> 3, k2 = ck2 & 7;
  const int x0 = xt * 16;
  const int tid = threadIdx.x;
  const int lane = tid & 63;
  const int w = tid >> 6;
  const int l15 = lane & 15, hig = lane >> 4;

  const float* slab = Ano + (size_t)c * ANO_C_STR + (size_t)k2 * ANO_K_STR + (size_t)x0 * ANO_X_STR;

  {
    const float* kp = kw + (size_t)tid * 512 + c * 64 + x0;
#pragma unroll
    for (int q = 0; q < 4; ++q) {
      float4 kv = ld4(kp + q * 4);
      ksl[(q * 4 + 0) * 256 + tid] = kv.x;
      ksl[(q * 4 + 1) * 256 + tid] = kv.y;
      ksl[(q * 4 + 2) * 256 + tid] = kv.z;
      ksl[(q * 4 + 3) * 256 + tid] = kv.w;
    }
  }
#pragma unroll
  for (int p = 0; p < 16; ++p) {
    int id = p * 256 + tid;
    int m = id >> 4, yq = id & 15;
    float4 v4 = ld4(vw + (size_t)m * 512 + k2 * 64 + yq * 4);
    unsigned sw = ((unsigned)m & 7u) << 2;
    int base = m * 32 + ((yq * 2) ^ (int)sw);
    vslw[base] = cvtpk(v4.x, v4.y);
    vslw[base + 1] = cvtpk(v4.z, v4.w);
  }

  int goff[4];
  int iw[4][4];
  bool wvalid[4];
#pragma unroll
  for (int j = 0; j < 4; ++j) {
    int u = tid + 256 * j;
    wvalid[j] = (u < 800);
    if (u >= 800) u = 799;
    int yp = u / 25, nq = u - yp * 25;
    goff[j] = yp * 200 + nq * 4;
#pragma unroll
    for (int e = 0; e < 4; ++e) {
      int n = nq * 4 + e;
      int s2 = (n ^ (n >> 3)) & 7;
      iw[j][e] = n * 32 + (yp ^ (s2 << 2));
    }
  }

  f32x4 acc[4][7];
#pragma unroll
  for (int mf = 0; mf < 4; ++mf)
#pragma unroll
    for (int nf = 0; nf < 7; ++nf) acc[mf][nf] = (f32x4)(0.f);

  float4 ra0[4], ra1[4], rb0[4], rb1[4];

#define LOADB(R0, R1, xx)                                     \
  {                                                           \
    const float* px_ = slab + (size_t)(xx)*ANO_X_STR;         \
    _Pragma("unroll") for (int j = 0; j < 4; ++j) {           \
      R0[j] = ld4(px_ + goff[j]);                             \
      R1[j] = ld4(px_ + goff[j] + 100);                       \
    }                                                         \
  }

#define WRITEB(BUF, R0, R1)                                   \
  {                                                           \
    unsigned* bp_ = &Bp[BUF][0];                              \
    _Pragma("unroll") for (int j = 0; j < 4; ++j)             \
      if (wvalid[j]) {                                        \
        bp_[iw[j][0]] = cvtpk(R0[j].x, R1[j].x);              \
        bp_[iw[j][1]] = cvtpk(R0[j].y, R1[j].y);              \
        bp_[iw[j][2]] = cvtpk(R0[j].z, R1[j].z);              \
        bp_[iw[j][3]] = cvtpk(R0[j].w, R1[j].w);              \
      }                                                       \
  }

#define COMPUTE(BUF, xx)                                                              \
  {                                                                                   \
    const unsigned short* bp16_ = (const unsigned short*)&Bp[BUF][0];                 \
    _Pragma("unroll") for (int ks = 0; ks < 2; ++ks) {                                \
      int chunk = ks * 4 + hig;                                                       \
      bf16x8 bfr[7];                                                                  \
      _Pragma("unroll") for (int nf = 0; nf < 7; ++nf) {                              \
        int r = nf * 16 + l15;                                                        \
        int slot = chunk ^ ((r ^ (r >> 3)) & 7);                                      \
        bfr[nf] = *(const bf16x8*)&bp16_[r * 64 + slot * 8];                          \
      }                                                                               \
      _Pragma("unroll") for (int mf = 0; mf < 4; ++mf) {                              \
        int m = w * 64 + mf * 16 + l15;                                               \
        float kx = ksl[(xx)*256 + m];                                                 \
        int slot = chunk ^ (m & 7);                                                   \
        const unsigned* vp = &vslw[m * 32 + slot * 4];                                \
        unsigned v0 = vp[0], v1 = vp[1], v2 = vp[2], v3 = vp[3];                      \
        union { unsigned u[4]; bf16x8 v; } fu;                                        \
        fu.u[0] = cvtpk(kx * bflo(v0), kx * bfhi(v0));                                \
        fu.u[1] = cvtpk(kx * bflo(v1), kx * bfhi(v1));                                \
        fu.u[2] = cvtpk(kx * bflo(v2), kx * bfhi(v2));                                \
        fu.u[3] = cvtpk(kx * bflo(v3), kx * bfhi(v3));                                \
        _Pragma("unroll") for (int nf = 0; nf < 7; ++nf)                              \
          acc[mf][nf] = __builtin_amdgcn_mfma_f32_16x16x32_bf16(fu.v, bfr[nf],        \
                                                                acc[mf][nf], 0, 0, 0);\
      }                                                                               \
    }                                                                                 \
  }

  LOADB(ra0, ra1, 0)
  LOADB(rb0, rb1, 1)

#pragma unroll 1
  for (int xx = 0; xx < 16; xx += 2) {
    WRITEB(0, ra0, ra1)
    if (xx + 2 < 16) LOADB(ra0, ra1, xx + 2)
    __syncthreads();
    COMPUTE(0, xx)
    WRITEB(1, rb0, rb1)
    if (xx + 3 < 16) LOADB(rb0, rb1, xx + 3)
    __syncthreads();
    COMPUTE(1, xx + 1)
  }

  float* sp = Spart + (size_t)bid * 25600;
#pragma unroll
  for (int mf = 0; mf < 4; ++mf)
#pragma unroll
    for (int nf = 0; nf < 7; ++nf) {
      int n = nf * 16 + l15;
      if (n < 100) {
#pragma unroll
        for (int rr = 0; rr < 4; ++rr) {
          int m = w * 64 + mf * 16 + hig * 4 + rr;
          sp[(size_t)m * 100 + n] = acc[mf][nf][rr];
        }
      }
    }
#undef LOADB
#undef WRITEB
#undef COMPUTE
}

// ---------------------------------------------------------------- k_Sred
__global__ __launch_bounds__(512) void k_Sred(const float* __restrict__ Spart,
                                              float* __restrict__ S) {
  __shared__ float red[512];
  const int m = blockIdx.x;
  const int tid = threadIdx.x;
  const int q = tid >> 7, n = tid & 127;
  float acc = 0.f;
  if (n < 100) {
    const float* p = Spart + (size_t)q * 64 * 25600 + (size_t)m * 100 + n;
#pragma unroll 8
    for (int s = 0; s < 64; ++s) acc += p[(size_t)s * 25600];
  }
  red[tid] = acc;
  __syncthreads();
  if (tid < 100)
    S[m * 100 + tid] = red[tid] + red[128 + tid] + red[256 + tid] + red[384 + tid];
}

// ---------------------------------------------------------------- k_scan2
// u[bp] = S[bp,30] + sum_i A^(2^i) S[bp,29-i]; squaring via MFMA (bf16 in, f32 acc).
// Ah[i][k]=hi(A[i][k]), ATh[j][k]=hi(A[k][j]); both [112][128] bf16, chunk-XOR swizzle
// slot = chunk ^ (row&7) (write and read use the same involution). C/D layout:
// col=lane&15, row=(lane>>4)*4+reg (verified). Matvec: f32 Ann (global) at i=0,
// bf16 A afterwards. Early-exit when max|A| < 1e-6.
__global__ __launch_bounds__(1024) void k_scan2(const float* __restrict__ Ann,
                                                const float* __restrict__ Sg,
                                                float* __restrict__ ug) {
  __shared__ __align__(16) unsigned short Ah[112 * 128];
  __shared__ __align__(16) unsigned short ATh[112 * 128];
  __shared__ float s_s[808];
  __shared__ float u_s[800];
  __shared__ float red[16];
  __shared__ float gmax_s;
  const int tid = threadIdx.x;
  const int lane = tid & 63;
  const int w = tid >> 6;  // wave 0..15
  const int l15 = lane & 15, hig = lane >> 4;

  {  // zero bf16 buffers (incl. pads) + s_s tail
    unsigned* za = (unsigned*)Ah;
    unsigned* zb = (unsigned*)ATh;
    for (int f = tid; f < 7168; f += 1024) { za[f] = 0u; zb[f] = 0u; }
    if (tid < 8) s_s[800 + tid] = 0.f;
  }
  for (int f = tid; f < 800; f += 1024) {
    int bp = f / 100, n = f - bp * 100;
    u_s[f] = Sg[(bp * 32 + 30) * 100 + n];
  }
  __syncthreads();

  float lmax0 = 0.f;
  for (int f = tid; f < 10000; f += 1024) {
    int i = f / 100, j = f - i * 100;
    float aval = Ann[f];
    lmax0 = fmaxf(lmax0, fabsf(aval));
    unsigned short hv = f2bf(aval);
    Ah[i * 128 + (((j >> 3) ^ (i & 7)) << 3) + (j & 7)] = hv;
    ATh[j * 128 + (((i >> 3) ^ (j & 7)) << 3) + (i & 7)] = hv;
  }
#pragma unroll
  for (int off = 32; off > 0; off >>= 1) lmax0 = fmaxf(lmax0, __shfl_down(lmax0, off, 64));
  if (lane == 0) red[w] = lmax0;
  __syncthreads();
  if (tid == 0) {
    float mx = 0.f;
    for (int q2 = 0; q2 < 16; ++q2) mx = fmaxf(mx, red[q2]);
    gmax_s = mx;
  }
  __syncthreads();

#pragma unroll 1
  for (int it = 0; it < 30; ++it) {
    const int t = 29 - it;
    for (int f = tid; f < 800; f += 1024) {
      int bp = f / 100, n = f - bp * 100;
      s_s[f] = Sg[(bp * 32 + t) * 100 + n];
    }
    __syncthreads();
    // ---- matvec: u[bp,n] += sum_m A[n,m] s[bp,m]
    if (tid < 800) {
      int bp = tid / 100, n = tid - bp * 100;
      const float* sr = &s_s[bp * 100];
      float a0 = 0.f;
      if (it == 0) {  // exact f32 from global (L2-hot, 40KB)
        const float* Ar = Ann + (size_t)n * 100;
#pragma unroll
        for (int mq = 0; mq < 25; ++mq) {
          float4 a4 = ld4(Ar + mq * 4);
          float4 s4 = ld4(sr + mq * 4);
          a0 += a4.x * s4.x + a4.y * s4.y + a4.z * s4.z + a4.w * s4.w;
        }
      } else {
        const unsigned short* Ar = &Ah[n * 128];
#pragma unroll
        for (int c = 0; c < 13; ++c) {
          u16x8 av = *(const u16x8*)&Ar[((c ^ (n & 7)) << 3)];
          float4 s4 = ld4(sr + c * 8);
          float4 s5 = ld4(sr + c * 8 + 4);
          a0 += bf2f(av[0]) * s4.x + bf2f(av[1]) * s4.y + bf2f(av[2]) * s4.z + bf2f(av[3]) * s4.w;
          a0 += bf2f(av[4]) * s5.x + bf2f(av[5]) * s5.y + bf2f(av[6]) * s5.z + bf2f(av[7]) * s5.w;
        }
      }
      u_s[tid] += a0;
    }
    if (it == 29) break;
    if (gmax_s < 1e-6f) break;  // remaining terms negligible (|A^2^i| < 1e-6)

    // ---- MFMA squaring: C[i][j] = sum_k Ah[i][k] * ATh[j][k]
    f32x4 accs[4];
#pragma unroll
    for (int s2 = 0; s2 < 4; ++s2) {
      accs[s2] = (f32x4)(0.f);
      int t2 = w + s2 * 16;
      if (t2 < 49) {
        int ti = t2 / 7, tj = t2 - ti * 7;
        int ra = ti * 16 + l15;
        int rb = tj * 16 + l15;
#pragma unroll
        for (int kc = 0; kc < 4; ++kc) {
          int q = kc * 4 + hig;
          bf16x8 af = *(const bf16x8*)&Ah[ra * 128 + ((q ^ (ra & 7)) << 3)];
          bf16x8 bfv = *(const bf16x8*)&ATh[rb * 128 + ((q ^ (rb & 7)) << 3)];
          accs[s2] = __builtin_amdgcn_mfma_f32_16x16x32_bf16(af, bfv, accs[s2], 0, 0, 0);
        }
      }
    }
    __syncthreads();  // all reads (matvec + MFMA) done before overwrite
    float lmax = 0.f;
#pragma unroll
    for (int s2 = 0; s2 < 4; ++s2) {
      int t2 = w + s2 * 16;
      if (t2 < 49) {
        int ti = t2 / 7, tj = t2 - ti * 7;
        int j = tj * 16 + l15;
#pragma unroll
        for (int r = 0; r < 4; ++r) {
          int i = ti * 16 + hig * 4 + r;
          if (i < 100 && j < 100) {
            float cv = accs[s2][r];
            unsigned short hv = f2bf(cv);
            Ah[i * 128 + (((j >> 3) ^ (i & 7)) << 3) + (j & 7)] = hv;
            ATh[j * 128 + (((i >> 3) ^ (j & 7)) << 3) + (i & 7)] = hv;
            lmax = fmaxf(lmax, fabsf(cv));
          }
        }
      }
    }
#pragma unroll
    for (int off = 32; off > 0; off >>= 1) lmax = fmaxf(lmax, __shfl_down(lmax, off, 64));
    if (lane == 0) red[w] = lmax;
    __syncthreads();
    if (tid == 0) {
      float mx = 0.f;
      for (int q2 = 0; q2 < 16; ++q2) mx = fmaxf(mx, red[q2]);
      gmax_s = mx;
    }
    __syncthreads();
  }
  __syncthreads();
  for (int f = tid; f < 800; f += 1024) ug[f] = u_s[f];
}

// ---------------------------------------------------------------- k_h3
// h[bp,a,b,g,d] = Aoo*k_last*v_last + sum_n Aon[abgd][n]*u[bp][n]
// grid 512 = ab(64) x gq(8); 8 panels (64d x 100n f32, pad-108 in LDS) per block.
// 2-deep register pipeline, 2 barriers / 2 panels. Row reads ds_read_b128
// (quad = (27d + n/4) mod 8: 2 lanes/quad = free); u reads wave-uniform b128.
__global__ __launch_bounds__(256) void k_h3(const float* __restrict__ Aon,
                                            const float* __restrict__ Aoo,
                                            const float* __restrict__ kw,
                                            const float* __restrict__ vw,
                                            const float* __restrict__ ug,
                                            float* __restrict__ h) {
  __shared__ float aonp[2][64 * 108];  // 55.3 KB
  __shared__ float u2[800];            // [bp][n]
  __shared__ float vl[512];            // [bp][d]
  __shared__ float kl[64];             // [bp][gi]
  __shared__ float aoo_s[512];         // [gi][d]
  const int bid = blockIdx.x;          // 512
  const int ab = bid >> 3, gq = bid & 7;
  const int a = ab >> 3, b = ab & 7;
  const int g0 = gq * 8;
  const int tid = threadIdx.x;
  const int d = tid & 63;
  const int pp = tid >> 6;
  const int bp0 = pp * 2, bp1 = pp * 2 + 1;

  for (int f = tid; f < 800; f += 256) u2[f] = ug[f];
  for (int f = tid; f < 512; f += 256) {
    int bp = f >> 6, dd = f & 63;
    vl[f] = vw[(size_t)(bp * 32 + 31) * 512 + b * 64 + dd];
  }
  if (tid < 64) {
    int bp = tid >> 3, gi = tid & 7;
    kl[tid] = kw[(size_t)(bp * 32 + 31) * 512 + a * 64 + g0 + gi];
  }
  if (tid < 128)
    *(float4*)&aoo_s[tid * 4] = ld4(Aoo + (size_t)ab * 4096 + (size_t)gq * 512 + tid * 4);

  const bool w7 = (tid < 64);
  int woff[7];
#pragma unroll
  for (int i = 0; i < 7; ++i) {
    int fi = (i < 6) ? (i * 256 + tid) : (1536 + (tid & 63));
    int ff = fi * 4;
    int dd = ff / 100;
    woff[i] = dd * 108 + (ff - dd * 100);  // float4-aligned (100 % 4 == 0)
  }
  const float* base0 = Aon + (size_t)(ab * 64 + g0) * 6400;

  float4 rA[7], rB[7];

#define LOADH(R, gi)                                              \
  {                                                               \
    const float* pb_ = base0 + (size_t)(gi)*6400;                 \
    _Pragma("unroll") for (int i = 0; i < 6; ++i)                 \
        R[i] = ld4(pb_ + (i * 256 + tid) * 4);                    \
    if (w7) R[6] = ld4(pb_ + (1536 + tid) * 4);                   \
  }

#define WRITEH(BUF, R)                                            \
  {                                                               \
    float* ap_ = &aonp[BUF][0];                                   \
    _Pragma("unroll") for (int i = 0; i < 6; ++i)                 \
        *(float4*)&ap_[woff[i]] = R[i];                           \
    if (w7) *(float4*)&ap_[woff[6]] = R[6];                       \
  }

#define COMPUTEH(BUF, gi)                                                        \
  {                                                                              \
    const float* row_ = &aonp[BUF][d * 108];                                     \
    float acc0 = 0.f, acc1 = 0.f;                                                \
    _Pragma("unroll") for (int nq = 0; nq < 25; ++nq) {                          \
      float4 x = ld4(row_ + nq * 4);                                             \
      float4 u0 = ld4(&u2[bp0 * 100 + nq * 4]);                                  \
      float4 u1 = ld4(&u2[bp1 * 100 + nq * 4]);                                  \
      acc0 += x.x * u0.x + x.y * u0.y + x.z * u0.z + x.w * u0.w;                 \
      acc1 += x.x * u1.x + x.y * u1.y + x.z * u1.z + x.w * u1.w;                 \
    }                                                                            \
    float av = aoo_s[(gi)*64 + d];                                               \
    size_t ob_ = (size_t)(ab * 64 + g0 + (gi)) * 64 + d;                         \
    h[(size_t)bp0 * 262144 + ob_] = av * kl[bp0 * 8 + (gi)] * vl[bp0 * 64 + d] + acc0; \
    h[(size_t)bp1 * 262144 + ob_] = av * kl[bp1 * 8 + (gi)] * vl[bp1 * 64 + d] + acc1; \
  }

  LOADH(rA, 0)
  LOADH(rB, 1)

#pragma unroll 1
  for (int gs = 0; gs < 8; gs += 2) {
    WRITEH(0, rA)
    if (gs + 2 < 8) LOADH(rA, gs + 2)
    __syncthreads();
    COMPUTEH(0, gs)
    WRITEH(1, rB)
    if (gs + 3 < 8) LOADH(rB, gs + 3)
    __syncthreads();
    COMPUTEH(1, gs + 1)
  }
#undef LOADH
#undef WRITEH
#undef COMPUTEH
}

// ---------------------------------------------------------------- k_y
__global__ __launch_bounds__(256) void k_y(const float* __restrict__ qw,
                                           const float* __restrict__ h,
                                           float* __restrict__ out) {
  __shared__ float qT[32 * 32];
  __shared__ float Hs[32 * 64];
  const int bid = blockIdx.x;  // bp*8 + b
  const int bp = bid >> 3, b = bid & 7;
  const int tid = threadIdx.x;
  const int r2 = tid >> 4, c2 = tid & 15;
  const size_t hbase = (size_t)bp * 262144 + (size_t)b * 4096;
  float acc[2][4];
#pragma unroll
  for (int i = 0; i < 2; ++i)
#pragma unroll
    for (int q = 0; q < 4; ++q) acc[i][q] = 0.f;

  for (int kc = 0; kc < 512; kc += 32) {
    {
      int t = tid & 31, kq = tid >> 5;
      float4 qv = ld4(qw + (size_t)(bp * 32 + t) * 512 + kc + kq * 4);
      qT[(kq * 4 + 0) * 32 + t] = qv.x;
      qT[(kq * 4 + 1) * 32 + t] = qv.y;
      qT[(kq * 4 + 2) * 32 + t] = qv.z;
      qT[(kq * 4 + 3) * 32 + t] = qv.w;
    }
#pragma unroll
    for (int i2 = 0; i2 < 2; ++i2) {
      int fid = i2 * 256 + tid;
      int kk = fid >> 4, xq = (fid & 15) * 4;
      int row = kc + kk;
      int A = row >> 6, G = row & 63;
      float4 hv = ld4(h + hbase + (size_t)A * 32768 + (size_t)G * 64 + xq);
      *(float4*)&Hs[kk * 64 + xq] = hv;
    }
    __syncthreads();
#pragma unroll
    for (int kk = 0; kk < 32; ++kk) {
      float2 q2 = *(const float2*)&qT[kk * 32 + r2 * 2];
      float4 h4 = ld4(&Hs[kk * 64 + c2 * 4]);
      acc[0][0] += q2.x * h4.x; acc[0][1] += q2.x * h4.y; acc[0][2] += q2.x * h4.z; acc[0][3] += q2.x * h4.w;
      acc[1][0] += q2.y * h4.x; acc[1][1] += q2.y * h4.y; acc[1][2] += q2.y * h4.z; acc[1][3] += q2.y * h4.w;
    }
    __syncthreads();
  }
#pragma unroll
  for (int i = 0; i < 2; ++i) {
    float4 v = make_float4(acc[i][0], acc[i][1], acc[i][2], acc[i][3]);
    *(float4*)&out[(size_t)(bp * 32 + r2 * 2 + i) * 512 + b * 64 + c2 * 4] = v;
  }
}

// ---------------------------------------------------------------- launch
extern "C" void kernel_launch(void* const* d_in, const int* in_sizes, int n_in,
                              void* d_out, int out_size, void* d_ws, size_t ws_size,
                              hipStream_t stream) {
  const float* x   = (const float*)d_in[0];
  const float* K   = (const float*)d_in[1];
  const float* Q   = (const float*)d_in[2];
  const float* V   = (const float*)d_in[3];
  const float* Aoo = (const float*)d_in[4];
  const float* Ann = (const float*)d_in[5];
  const float* Aon = (const float*)d_in[6];
  const float* Ano = (const float*)d_in[7];
  float* out = (float*)d_out;

  float* ws = (float*)d_ws;
  float* kw  = ws;                                          // 131072
  float* qw  = kw + 131072;                                 // 131072
  float* vw  = qw + 131072;                                 // 131072
  float* S   = ws + 458752;                                 // 25600
  float* u   = S + 25600;                                   // 800
  unsigned short* A2  = (unsigned short*)(ws + 485152);     // 393216 u16
  unsigned short* Bw  = (unsigned short*)(ws + 681760);     // 2359296 u16
  float* h     = ws + 1861408;                              // 2097152
  float* Spart = ws + 3958560;                              // 6553600 (26.2 MB)

  k_prep<<<dim3(256), dim3(256), 0, stream>>>(x, A2);
  k_cvtW<<<dim3(1536), dim3(128), 0, stream>>>(K, Q, V, Bw);
  k_kqv3<<<dim3(24), dim3(256), 0, stream>>>(A2, Bw, kw);
  k_S4<<<dim3(256), dim3(256), 0, stream>>>(kw, vw, Ano, Spart);
  k_Sred<<<dim3(256), dim3(512), 0, stream>>>(Spart, S);
  k_scan2<<<dim3(1), dim3(1024), 0, stream>>>(Ann, S, u);
  k_h3<<<dim3(512), dim3(256), 0, stream>>>(Aon, Aoo, kw, vw, u, h);
  k_y<<<dim3(64), dim3(256), 0, stream>>>(qw, h, out);
}

// Round 11
// 154.790 us; speedup vs baseline: 1.2513x; 1.0422x over previous
//
#include <hip/hip_runtime.h>

// GateLoopOperator, MI355X. Round 11:
//  - k_h4: Aon panels staged via global_load_lds dwordx4 into linear [64][100] f32 LDS
//    (bank-free b128 row reads), 1 barrier/panel, 2 blocks/CU.
//  - Spart stored bf16 (halves the 26 MB intermediate).
//  - k_pc: merged prep+cvtW. k_scan2: 2 barriers/iter.
//
// Pipeline:
//  k_pc   : A2 = [hi(xp)|hi(xp)|lo(xp)] ; Bw = [hi(W)|lo|hi]
//  k_kqv3 : k/q/v f32 = A2 @ Bw^T (split-bf16 MFMA => f32 quality)
//  k_S4   : Spart(bf16) = sum_{x,y} bf16(k v) * bf16(Ano)  (2-deep reg pipeline)
//  k_Sred : S = sum over 256 slabs
//  k_scan2: u[bp] = S[bp,30] + sum_i A^(2^i) S[bp,29-i]  (MFMA squaring, early-exit)
//  k_h4   : h = Aoo*k_last*v_last + Aon . u
//  k_y    : y = q . h

#define ANO_C_STR 3276800
#define ANO_K_STR 409600
#define ANO_X_STR 6400

typedef __attribute__((ext_vector_type(8))) short bf16x8;
typedef __attribute__((ext_vector_type(4))) float f32x4;
typedef __attribute__((ext_vector_type(4))) unsigned short u16x4;
typedef __attribute__((ext_vector_type(8))) unsigned short u16x8;

__device__ __forceinline__ float4 ld4(const float* p) { return *(const float4*)p; }

__device__ __forceinline__ unsigned short f2bf(float f) {  // RNE
  unsigned u = __float_as_uint(f);
  unsigned r = (u + 0x7fffu + ((u >> 16) & 1u)) >> 16;
  return (unsigned short)r;
}
__device__ __forceinline__ float bf2f(unsigned short b) {
  return __uint_as_float(((unsigned)b) << 16);
}
__device__ __forceinline__ unsigned cvtpk(float lo, float hi) {
  unsigned r;
  asm("v_cvt_pk_bf16_f32 %0, %1, %2" : "=v"(r) : "v"(lo), "v"(hi));
  return r;
}
__device__ __forceinline__ float bflo(unsigned u) { return __uint_as_float(u << 16); }
__device__ __forceinline__ float bfhi(unsigned u) { return __uint_as_float(u & 0xffff0000u); }

// ---------------------------------------------------------------- k_pc (prep + cvtW merged)
__global__ __launch_bounds__(256) void k_pc(const float* __restrict__ X,
                                            const float* __restrict__ Km,
                                            const float* __restrict__ Qm,
                                            const float* __restrict__ Vm,
                                            unsigned short* __restrict__ A2,
                                            unsigned short* __restrict__ Bw) {
  const int bid = blockIdx.x;
  const int tid = threadIdx.x;
  if (bid < 256) {
    __shared__ float xs[512];
    const int m = bid;
    for (int f = tid; f < 512; f += 256) xs[f] = X[m * 512 + f];
    __syncthreads();
    for (int f = tid; f < 512; f += 256) {
      float v = xs[((f & 7) << 6) | (f >> 3)];
      unsigned short hi = f2bf(v);
      unsigned short lo = f2bf(v - bf2f(hi));
      A2[(size_t)m * 1536 + f] = hi;
      A2[(size_t)m * 1536 + 512 + f] = hi;
      A2[(size_t)m * 1536 + 1024 + f] = lo;
    }
  } else {
    const int j = (bid - 256) * 2 + (tid >> 7);  // mat*512 + o
    const int t = tid & 127;
    const int mat = j >> 9, o = j & 511;
    const int r = ((o & 63) << 3) | (o >> 6);
    const float* W = ((mat == 0) ? Km : ((mat == 1) ? Qm : Vm)) + (size_t)r * 512;
    float4 v = ld4(W + t * 4);
    u16x4 hi, lo;
    float vv[4] = {v.x, v.y, v.z, v.w};
#pragma unroll
    for (int e = 0; e < 4; ++e) {
      hi[e] = f2bf(vv[e]);
      lo[e] = f2bf(vv[e] - bf2f(hi[e]));
    }
    *(u16x4*)&Bw[(size_t)j * 1536 + t * 4] = hi;
    *(u16x4*)&Bw[(size_t)j * 1536 + 512 + t * 4] = lo;
    *(u16x4*)&Bw[(size_t)j * 1536 + 1024 + t * 4] = hi;
  }
}

// ---------------------------------------------------------------- k_kqv3
__global__ __launch_bounds__(256) void k_kqv3(const unsigned short* __restrict__ A2,
                                              const unsigned short* __restrict__ Bw,
                                              float* __restrict__ kqvF) {
  __shared__ __align__(16) unsigned short Asm[128 * 64];
  __shared__ __align__(16) unsigned short Bsm[128 * 64];
  const int bid = blockIdx.x;  // 24
  const int mt = bid & 1, jt = bid >> 1;
  const int m0 = mt * 128, j0 = jt * 128;
  const int tid = threadIdx.x;
  const int lane = tid & 63;
  const int w = tid >> 6;
  const int wm = w >> 1, wn = w & 1;

  f32x4 acc[4][4];
#pragma unroll
  for (int a = 0; a < 4; ++a)
#pragma unroll
    for (int b = 0; b < 4; ++b) acc[a][b] = (f32x4)(0.f);

  for (int kc = 0; kc < 1536; kc += 64) {
#pragma unroll
    for (int cch = 0; cch < 4; ++cch) {
      int sid = cch * 256 + tid;
      int r = sid >> 3, c8 = sid & 7;
      int srcc = c8 ^ (r & 7);
      const unsigned short* ga = A2 + (size_t)(m0 + r) * 1536 + kc + srcc * 8;
      __builtin_amdgcn_global_load_lds((const __attribute__((address_space(1))) unsigned int*)ga,
                                       (__attribute__((address_space(3))) unsigned int*)(&Asm[sid * 8]),
                                       16, 0, 0);
      const unsigned short* gb = Bw + (size_t)(j0 + r) * 1536 + kc + srcc * 8;
      __builtin_amdgcn_global_load_lds((const __attribute__((address_space(1))) unsigned int*)gb,
                                       (__attribute__((address_space(3))) unsigned int*)(&Bsm[sid * 8]),
                                       16, 0, 0);
    }
    __syncthreads();
#pragma unroll
    for (int ks = 0; ks < 2; ++ks) {
      bf16x8 af[4], bfr[4];
#pragma unroll
      for (int mf = 0; mf < 4; ++mf) {
        int r = wm * 64 + mf * 16 + (lane & 15);
        int slot = (ks * 4 + (lane >> 4)) ^ (r & 7);
        af[mf] = *(const bf16x8*)&Asm[r * 64 + slot * 8];
      }
#pragma unroll
      for (int nf = 0; nf < 4; ++nf) {
        int r = wn * 64 + nf * 16 + (lane & 15);
        int slot = (ks * 4 + (lane >> 4)) ^ (r & 7);
        bfr[nf] = *(const bf16x8*)&Bsm[r * 64 + slot * 8];
      }
#pragma unroll
      for (int mf = 0; mf < 4; ++mf)
#pragma unroll
        for (int nf = 0; nf < 4; ++nf)
          acc[mf][nf] = __builtin_amdgcn_mfma_f32_16x16x32_bf16(af[mf], bfr[nf], acc[mf][nf], 0, 0, 0);
    }
    __syncthreads();
  }
#pragma unroll
  for (int mf = 0; mf < 4; ++mf)
#pragma unroll
    for (int nf = 0; nf < 4; ++nf) {
      int col = j0 + wn * 64 + nf * 16 + (lane & 15);
      int mat = col >> 9, o = col & 511;
      float* Outp = kqvF + (size_t)mat * 131072;
#pragma unroll
      for (int r = 0; r < 4; ++r) {
        int row = m0 + wm * 64 + mf * 16 + (lane >> 4) * 4 + r;
        Outp[(size_t)row * 512 + o] = acc[mf][nf][r];
      }
    }
}

// ---------------------------------------------------------------- k_S4 (bf16 Spart)
__global__ __launch_bounds__(256) void k_S4(const float* __restrict__ kw,
                                            const float* __restrict__ vw,
                                            const float* __restrict__ Ano,
                                            unsigned short* __restrict__ Spart) {
  __shared__ float ksl[16 * 256];
  __shared__ unsigned vslw[256 * 32];
  __shared__ __align__(16) unsigned Bp[2][112 * 32];
  const int bid = blockIdx.x;  // 256
  const int ck2 = bid & 63, xt = bid >> 6;
  const int c = ck2 >> 3, k2 = ck2 & 7;
  const int x0 = xt * 16;
  const int tid = threadIdx.x;
  const int lane = tid & 63;
  const int w = tid >> 6;
  const int l15 = lane & 15, hig = lane >> 4;

  const float* slab = Ano + (size_t)c * ANO_C_STR + (size_t)k2 * ANO_K_STR + (size_t)x0 * ANO_X_STR;

  {
    const float* kp = kw + (size_t)tid * 512 + c * 64 + x0;
#pragma unroll
    for (int q = 0; q < 4; ++q) {
      float4 kv = ld4(kp + q * 4);
      ksl[(q * 4 + 0) * 256 + tid] = kv.x;
      ksl[(q * 4 + 1) * 256 + tid] = kv.y;
      ksl[(q * 4 + 2) * 256 + tid] = kv.z;
      ksl[(q * 4 + 3) * 256 + tid] = kv.w;
    }
  }
#pragma unroll
  for (int p = 0; p < 16; ++p) {
    int id = p * 256 + tid;
    int m = id >> 4, yq = id & 15;
    float4 v4 = ld4(vw + (size_t)m * 512 + k2 * 64 + yq * 4);
    unsigned sw = ((unsigned)m & 7u) << 2;
    int base = m * 32 + ((yq * 2) ^ (int)sw);
    vslw[base] = cvtpk(v4.x, v4.y);
    vslw[base + 1] = cvtpk(v4.z, v4.w);
  }

  int goff[4];
  int iw[4][4];
  bool wvalid[4];
#pragma unroll
  for (int j = 0; j < 4; ++j) {
    int u = tid + 256 * j;
    wvalid[j] = (u < 800);
    if (u >= 800) u = 799;
    int yp = u / 25, nq = u - yp * 25;
    goff[j] = yp * 200 + nq * 4;
#pragma unroll
    for (int e = 0; e < 4; ++e) {
      int n = nq * 4 + e;
      int s2 = (n ^ (n >> 3)) & 7;
      iw[j][e] = n * 32 + (yp ^ (s2 << 2));
    }
  }

  f32x4 acc[4][7];
#pragma unroll
  for (int mf = 0; mf < 4; ++mf)
#pragma unroll
    for (int nf = 0; nf < 7; ++nf) acc[mf][nf] = (f32x4)(0.f);

  float4 ra0[4], ra1[4], rb0[4], rb1[4];

#define LOADB(R0, R1, xx)                                     \
  {                                                           \
    const float* px_ = slab + (size_t)(xx)*ANO_X_STR;         \
    _Pragma("unroll") for (int j = 0; j < 4; ++j) {           \
      R0[j] = ld4(px_ + goff[j]);                             \
      R1[j] = ld4(px_ + goff[j] + 100);                       \
    }                                                         \
  }

#define WRITEB(BUF, R0, R1)                                   \
  {                                                           \
    unsigned* bp_ = &Bp[BUF][0];                              \
    _Pragma("unroll") for (int j = 0; j < 4; ++j)             \
      if (wvalid[j]) {                                        \
        bp_[iw[j][0]] = cvtpk(R0[j].x, R1[j].x);              \
        bp_[iw[j][1]] = cvtpk(R0[j].y, R1[j].y);              \
        bp_[iw[j][2]] = cvtpk(R0[j].z, R1[j].z);              \
        bp_[iw[j][3]] = cvtpk(R0[j].w, R1[j].w);              \
      }                                                       \
  }

#define COMPUTE(BUF, xx)                                                              \
  {                                                                                   \
    const unsigned short* bp16_ = (const unsigned short*)&Bp[BUF][0];                 \
    _Pragma("unroll") for (int ks = 0; ks < 2; ++ks) {                                \
      int chunk = ks * 4 + hig;                                                       \
      bf16x8 bfr[7];                                                                  \
      _Pragma("unroll") for (int nf = 0; nf < 7; ++nf) {                              \
        int r = nf * 16 + l15;                                                        \
        int slot = chunk ^ ((r ^ (r >> 3)) & 7);                                      \
        bfr[nf] = *(const bf16x8*)&bp16_[r * 64 + slot * 8];                          \
      }                                                                               \
      _Pragma("unroll") for (int mf = 0; mf < 4; ++mf) {                              \
        int m = w * 64 + mf * 16 + l15;                                               \
        float kx = ksl[(xx)*256 + m];                                                 \
        int slot = chunk ^ (m & 7);                                                   \
        const unsigned* vp = &vslw[m * 32 + slot * 4];                                \
        unsigned v0 = vp[0], v1 = vp[1], v2 = vp[2], v3 = vp[3];                      \
        union { unsigned u[4]; bf16x8 v; } fu;                                        \
        fu.u[0] = cvtpk(kx * bflo(v0), kx * bfhi(v0));                                \
        fu.u[1] = cvtpk(kx * bflo(v1), kx * bfhi(v1));                                \
        fu.u[2] = cvtpk(kx * bflo(v2), kx * bfhi(v2));                                \
        fu.u[3] = cvtpk(kx * bflo(v3), kx * bfhi(v3));                                \
        _Pragma("unroll") for (int nf = 0; nf < 7; ++nf)                              \
          acc[mf][nf] = __builtin_amdgcn_mfma_f32_16x16x32_bf16(fu.v, bfr[nf],        \
                                                                acc[mf][nf], 0, 0, 0);\
      }                                                                               \
    }                                                                                 \
  }

  LOADB(ra0, ra1, 0)
  LOADB(rb0, rb1, 1)

#pragma unroll 1
  for (int xx = 0; xx < 16; xx += 2) {
    WRITEB(0, ra0, ra1)
    if (xx + 2 < 16) LOADB(ra0, ra1, xx + 2)
    __syncthreads();
    COMPUTE(0, xx)
    WRITEB(1, rb0, rb1)
    if (xx + 3 < 16) LOADB(rb0, rb1, xx + 3)
    __syncthreads();
    COMPUTE(1, xx + 1)
  }

  unsigned short* sp = Spart + (size_t)bid * 25600;
#pragma unroll
  for (int mf = 0; mf < 4; ++mf)
#pragma unroll
    for (int nf = 0; nf < 7; ++nf) {
      int n = nf * 16 + l15;
      if (n < 100) {
#pragma unroll
        for (int rr = 0; rr < 4; ++rr) {
          int m = w * 64 + mf * 16 + hig * 4 + rr;
          sp[(size_t)m * 100 + n] = f2bf(acc[mf][nf][rr]);
        }
      }
    }
#undef LOADB
#undef WRITEB
#undef COMPUTE
}

// ---------------------------------------------------------------- k_Sred (bf16 in)
__global__ __launch_bounds__(512) void k_Sred(const unsigned short* __restrict__ Spart,
                                              float* __restrict__ S) {
  __shared__ float red[512];
  const int m = blockIdx.x;
  const int tid = threadIdx.x;
  const int q = tid >> 7, n = tid & 127;
  float acc = 0.f;
  if (n < 100) {
    const unsigned short* p = Spart + (size_t)q * 64 * 25600 + (size_t)m * 100 + n;
#pragma unroll 8
    for (int s = 0; s < 64; ++s) acc += bf2f(p[(size_t)s * 25600]);
  }
  red[tid] = acc;
  __syncthreads();
  if (tid < 100)
    S[m * 100 + tid] = red[tid] + red[128 + tid] + red[256 + tid] + red[384 + tid];
}

// ---------------------------------------------------------------- k_scan2 (2 barriers/iter)
__global__ __launch_bounds__(1024) void k_scan2(const float* __restrict__ Ann,
                                                const float* __restrict__ Sg,
                                                float* __restrict__ ug) {
  __shared__ __align__(16) unsigned short Ah[112 * 128];
  __shared__ __align__(16) unsigned short ATh[112 * 128];
  __shared__ float s_s[808];
  __shared__ float u_s[800];
  __shared__ float red[16];
  const int tid = threadIdx.x;
  const int lane = tid & 63;
  const int w = tid >> 6;  // 0..15
  const int l15 = lane & 15, hig = lane >> 4;

  {
    unsigned* za = (unsigned*)Ah;
    unsigned* zb = (unsigned*)ATh;
    for (int f = tid; f < 7168; f += 1024) { za[f] = 0u; zb[f] = 0u; }
    if (tid < 8) s_s[800 + tid] = 0.f;
  }
  for (int f = tid; f < 800; f += 1024) {
    int bp = f / 100, n = f - bp * 100;
    u_s[f] = Sg[(bp * 32 + 30) * 100 + n];
  }
  __syncthreads();

  float lmax0 = 0.f;
  for (int f = tid; f < 10000; f += 1024) {
    int i = f / 100, j = f - i * 100;
    float aval = Ann[f];
    lmax0 = fmaxf(lmax0, fabsf(aval));
    unsigned short hv = f2bf(aval);
    Ah[i * 128 + (((j >> 3) ^ (i & 7)) << 3) + (j & 7)] = hv;
    ATh[j * 128 + (((i >> 3) ^ (j & 7)) << 3) + (i & 7)] = hv;
  }
#pragma unroll
  for (int off = 32; off > 0; off >>= 1) lmax0 = fmaxf(lmax0, __shfl_down(lmax0, off, 64));
  if (lane == 0) red[w] = lmax0;

#pragma unroll 1
  for (int it = 0; it < 30; ++it) {
    const int t = 29 - it;
    for (int f = tid; f < 800; f += 1024) {
      int bp = f / 100, n = f - bp * 100;
      s_s[f] = Sg[(bp * 32 + t) * 100 + n];
    }
    __syncthreads();  // s_s ready; red[]/Ah writes from prev iter visible
    float gmax = 0.f;
#pragma unroll
    for (int q2 = 0; q2 < 16; ++q2) gmax = fmaxf(gmax, red[q2]);
    // ---- matvec: u[bp,n] += sum_m A[n,m] s[bp,m]
    if (tid < 800) {
      int bp = tid / 100, n = tid - bp * 100;
      const float* sr = &s_s[bp * 100];
      float a0 = 0.f;
      if (it == 0) {
        const float* Ar = Ann + (size_t)n * 100;
#pragma unroll
        for (int mq = 0; mq < 25; ++mq) {
          float4 a4 = ld4(Ar + mq * 4);
          float4 s4 = ld4(sr + mq * 4);
          a0 += a4.x * s4.x + a4.y * s4.y + a4.z * s4.z + a4.w * s4.w;
        }
      } else {
        const unsigned short* Ar = &Ah[n * 128];
#pragma unroll
        for (int c = 0; c < 13; ++c) {
          u16x8 av = *(const u16x8*)&Ar[((c ^ (n & 7)) << 3)];
          float4 s4 = ld4(sr + c * 8);
          float4 s5 = ld4(sr + c * 8 + 4);
          a0 += bf2f(av[0]) * s4.x + bf2f(av[1]) * s4.y + bf2f(av[2]) * s4.z + bf2f(av[3]) * s4.w;
          a0 += bf2f(av[4]) * s5.x + bf2f(av[5]) * s5.y + bf2f(av[6]) * s5.z + bf2f(av[7]) * s5.w;
        }
      }
      u_s[tid] += a0;
    }
    if (it == 29) break;
    if (gmax < 1e-6f) break;

    // ---- MFMA squaring: C[i][j] = sum_k Ah[i][k] * ATh[j][k]
    f32x4 accs[4];
#pragma unroll
    for (int s2 = 0; s2 < 4; ++s2) {
      accs[s2] = (f32x4)(0.f);
      int t2 = w + s2 * 16;
      if (t2 < 49) {
        int ti = t2 / 7, tj = t2 - ti * 7;
        int ra = ti * 16 + l15;
        int rb = tj * 16 + l15;
#pragma unroll
        for (int kc = 0; kc < 4; ++kc) {
          int q = kc * 4 + hig;
          bf16x8 af = *(const bf16x8*)&Ah[ra * 128 + ((q ^ (ra & 7)) << 3)];
          bf16x8 bfv = *(const bf16x8*)&ATh[rb * 128 + ((q ^ (rb & 7)) << 3)];
          accs[s2] = __builtin_amdgcn_mfma_f32_16x16x32_bf16(af, bfv, accs[s2], 0, 0, 0);
        }
      }
    }
    __syncthreads();  // matvec + MFMA reads complete before overwrite
    float lmax = 0.f;
#pragma unroll
    for (int s2 = 0; s2 < 4; ++s2) {
      int t2 = w + s2 * 16;
      if (t2 < 49) {
        int ti = t2 / 7, tj = t2 - ti * 7;
        int j = tj * 16 + l15;
#pragma unroll
        for (int r = 0; r < 4; ++r) {
          int i = ti * 16 + hig * 4 + r;
          if (i < 100 && j < 100) {
            float cv = accs[s2][r];
            unsigned short hv = f2bf(cv);
            Ah[i * 128 + (((j >> 3) ^ (i & 7)) << 3) + (j & 7)] = hv;
            ATh[j * 128 + (((i >> 3) ^ (j & 7)) << 3) + (i & 7)] = hv;
            lmax = fmaxf(lmax, fabsf(cv));
          }
        }
      }
    }
#pragma unroll
    for (int off = 32; off > 0; off >>= 1) lmax = fmaxf(lmax, __shfl_down(lmax, off, 64));
    if (lane == 0) red[w] = lmax;
    // next iteration's staging barrier orders red/Ah writes before reads
  }
  __syncthreads();
  for (int f = tid; f < 800; f += 1024) ug[f] = u_s[f];
}

// ---------------------------------------------------------------- k_h4
// h[bp,a,b,g,d] = Aoo*k_last*v_last + sum_n Aon[abgd][n]*u[bp][n]
// grid 512 = ab(64) x gq(8); 8 panels/block; panels staged DIRECTLY into linear
// [64][100] f32 LDS via global_load_lds dwordx4 (no reg round-trip, no LDS writes).
// Row reads b128: bank start 4(d+nq) mod 32 -> 2 lanes/bank (free). 2 blocks/CU.
__global__ __launch_bounds__(256, 2) void k_h4(const float* __restrict__ Aon,
                                               const float* __restrict__ Aoo,
                                               const float* __restrict__ kw,
                                               const float* __restrict__ vw,
                                               const float* __restrict__ ug,
                                               float* __restrict__ h) {
  __shared__ __align__(16) float ap[2][6400];  // 51.2 KB
  __shared__ float u2[800];
  __shared__ float vl[512];
  __shared__ float kl[64];
  __shared__ float aoo_s[512];
  const int bid = blockIdx.x;  // 512
  const int ab = bid >> 3, gq = bid & 7;
  const int a = ab >> 3, b = ab & 7;
  const int g0 = gq * 8;
  const int tid = threadIdx.x;
  const int d = tid & 63;
  const int pp = tid >> 6;
  const int bp0 = pp * 2, bp1 = pp * 2 + 1;

  for (int f = tid; f < 800; f += 256) u2[f] = ug[f];
  for (int f = tid; f < 512; f += 256) {
    int bp = f >> 6, dd = f & 63;
    vl[f] = vw[(size_t)(bp * 32 + 31) * 512 + b * 64 + dd];
  }
  if (tid < 64) {
    int bp = tid >> 3, gi = tid & 7;
    kl[tid] = kw[(size_t)(bp * 32 + 31) * 512 + a * 64 + g0 + gi];
  }
  if (tid < 128)
    *(float4*)&aoo_s[tid * 4] = ld4(Aoo + (size_t)ab * 4096 + (size_t)gq * 512 + tid * 4);

  const float* base0 = Aon + (size_t)(ab * 64 + g0) * 6400;

#define STAGEH(BUF, gi)                                                                     \
  {                                                                                         \
    const float* pb_ = base0 + (size_t)(gi)*6400;                                           \
    float* dst_ = &ap[BUF][0];                                                              \
    _Pragma("unroll") for (int i = 0; i < 6; ++i)                                           \
        __builtin_amdgcn_global_load_lds(                                                   \
            (const __attribute__((address_space(1))) unsigned int*)(pb_ + (i * 256 + tid) * 4), \
            (__attribute__((address_space(3))) unsigned int*)(dst_ + (i * 256 + tid) * 4),  \
            16, 0, 0);                                                                      \
    if (tid < 64)                                                                           \
      __builtin_amdgcn_global_load_lds(                                                     \
          (const __attribute__((address_space(1))) unsigned int*)(pb_ + (1536 + tid) * 4),  \
          (__attribute__((address_space(3))) unsigned int*)(dst_ + (1536 + tid) * 4),       \
          16, 0, 0);                                                                        \
  }

#define COMPUTEH(BUF, gi)                                                        \
  {                                                                              \
    const float* row_ = &ap[BUF][d * 100];                                       \
    float acc0 = 0.f, acc1 = 0.f;                                                \
    _Pragma("unroll") for (int nq = 0; nq < 25; ++nq) {                          \
      float4 x = ld4(row_ + nq * 4);                                             \
      float4 u0 = ld4(&u2[bp0 * 100 + nq * 4]);                                  \
      float4 u1 = ld4(&u2[bp1 * 100 + nq * 4]);                                  \
      acc0 += x.x * u0.x + x.y * u0.y + x.z * u0.z + x.w * u0.w;                 \
      acc1 += x.x * u1.x + x.y * u1.y + x.z * u1.z + x.w * u1.w;                 \
    }                                                                            \
    float av = aoo_s[(gi)*64 + d];                                               \
    size_t ob_ = (size_t)(ab * 64 + g0 + (gi)) * 64 + d;                         \
    h[(size_t)bp0 * 262144 + ob_] = av * kl[bp0 * 8 + (gi)] * vl[bp0 * 64 + d] + acc0; \
    h[(size_t)bp1 * 262144 + ob_] = av * kl[bp1 * 8 + (gi)] * vl[bp1 * 64 + d] + acc1; \
  }

  STAGEH(0, 0)
  __syncthreads();  // drains panel-0 loads (+ small staging)

#pragma unroll 1
  for (int gi = 0; gi < 8; ++gi) {
    if (gi + 1 < 8) STAGEH((gi + 1) & 1, gi + 1)
    COMPUTEH(gi & 1, gi)
    __syncthreads();  // drains next panel's loads; orders buffer reuse
  }
#undef STAGEH
#undef COMPUTEH
}

// ---------------------------------------------------------------- k_y
__global__ __launch_bounds__(256) void k_y(const float* __restrict__ qw,
                                           const float* __restrict__ h,
                                           float* __restrict__ out) {
  __shared__ float qT[32 * 32];
  __shared__ float Hs[32 * 64];
  const int bid = blockIdx.x;  // bp*8 + b
  const int bp = bid >> 3, b = bid & 7;
  const int tid = threadIdx.x;
  const int r2 = tid >> 4, c2 = tid & 15;
  const size_t hbase = (size_t)bp * 262144 + (size_t)b * 4096;
  float acc[2][4];
#pragma unroll
  for (int i = 0; i < 2; ++i)
#pragma unroll
    for (int q = 0; q < 4; ++q) acc[i][q] = 0.f;

  for (int kc = 0; kc < 512; kc += 32) {
    {
      int t = tid & 31, kq = tid >> 5;
      float4 qv = ld4(qw + (size_t)(bp * 32 + t) * 512 + kc + kq * 4);
      qT[(kq * 4 + 0) * 32 + t] = qv.x;
      qT[(kq * 4 + 1) * 32 + t] = qv.y;
      qT[(kq * 4 + 2) * 32 + t] = qv.z;
      qT[(kq * 4 + 3) * 32 + t] = qv.w;
    }
#pragma unroll
    for (int i2 = 0; i2 < 2; ++i2) {
      int fid = i2 * 256 + tid;
      int kk = fid >> 4, xq = (fid & 15) * 4;
      int row = kc + kk;
      int A = row >> 6, G = row & 63;
      float4 hv = ld4(h + hbase + (size_t)A * 32768 + (size_t)G * 64 + xq);
      *(float4*)&Hs[kk * 64 + xq] = hv;
    }
    __syncthreads();
#pragma unroll
    for (int kk = 0; kk < 32; ++kk) {
      float2 q2 = *(const float2*)&qT[kk * 32 + r2 * 2];
      float4 h4 = ld4(&Hs[kk * 64 + c2 * 4]);
      acc[0][0] += q2.x * h4.x; acc[0][1] += q2.x * h4.y; acc[0][2] += q2.x * h4.z; acc[0][3] += q2.x * h4.w;
      acc[1][0] += q2.y * h4.x; acc[1][1] += q2.y * h4.y; acc[1][2] += q2.y * h4.z; acc[1][3] += q2.y * h4.w;
    }
    __syncthreads();
  }
#pragma unroll
  for (int i = 0; i < 2; ++i) {
    float4 v = make_float4(acc[i][0], acc[i][1], acc[i][2], acc[i][3]);
    *(float4*)&out[(size_t)(bp * 32 + r2 * 2 + i) * 512 + b * 64 + c2 * 4] = v;
  }
}

// ---------------------------------------------------------------- launch
extern "C" void kernel_launch(void* const* d_in, const int* in_sizes, int n_in,
                              void* d_out, int out_size, void* d_ws, size_t ws_size,
                              hipStream_t stream) {
  const float* x   = (const float*)d_in[0];
  const float* K   = (const float*)d_in[1];
  const float* Q   = (const float*)d_in[2];
  const float* V   = (const float*)d_in[3];
  const float* Aoo = (const float*)d_in[4];
  const float* Ann = (const float*)d_in[5];
  const float* Aon = (const float*)d_in[6];
  const float* Ano = (const float*)d_in[7];
  float* out = (float*)d_out;

  float* ws = (float*)d_ws;
  float* kw  = ws;                                          // 131072
  float* qw  = kw + 131072;                                 // 131072
  float* vw  = qw + 131072;                                 // 131072
  float* S   = ws + 458752;                                 // 25600
  float* u   = S + 25600;                                   // 800
  unsigned short* A2  = (unsigned short*)(ws + 485152);     // 393216 u16
  unsigned short* Bw  = (unsigned short*)(ws + 681760);     // 2359296 u16
  float* h     = ws + 1861408;                              // 2097152
  unsigned short* Spart = (unsigned short*)(ws + 3958560);  // 6553600 u16 (13.1 MB)

  k_pc<<<dim3(1024), dim3(256), 0, stream>>>(x, K, Q, V, A2, Bw);
  k_kqv3<<<dim3(24), dim3(256), 0, stream>>>(A2, Bw, kw);
  k_S4<<<dim3(256), dim3(256), 0, stream>>>(kw, vw, Ano, Spart);
  k_Sred<<<dim3(256), dim3(512), 0, stream>>>(Spart, S);
  k_scan2<<<dim3(1), dim3(1024), 0, stream>>>(Ann, S, u);
  k_h4<<<dim3(512), dim3(256), 0, stream>>>(Aon, Aoo, kw, vw, u, h);
  k_y<<<dim3(64), dim3(256), 0, stream>>>(qw, h, out);
}